// Round 1
// baseline (461.269 us; speedup 1.0000x reference)
//
#include <hip/hip_runtime.h>

#define NN 100000
#define EE 640000
#define D 128

// ---------------------------------------------------------------------------
// Kernel 1: scatter-aggregate.  agg[dst] += w * x[src]  (agg lives in d_out)
// 128 threads per edge (one per feature). Coalesced x reads (512B/edge),
// HW f32 atomics into agg.
// ---------------------------------------------------------------------------
__global__ __launch_bounds__(256) void scatter_kernel(
    const float* __restrict__ x,
    const int*   __restrict__ ei,   // [2][E]: row0=src, row1=dst
    const float* __restrict__ ew,
    float*       agg)
{
    int gid = blockIdx.x * 256 + threadIdx.x;
    int e = gid >> 7;
    int f = gid & 127;
    if (e >= EE) return;
    int   src = ei[e];
    int   dst = ei[EE + e];
    float w   = ew[e];
    float v   = x[src * D + f] * w;
    unsafeAtomicAdd(&agg[dst * D + f], v);
}

// ---------------------------------------------------------------------------
// Kernel 2: out = agg @ Wrel^T + x @ Wroot^T + b, in place (agg == out).
// Block: 512 threads = 8 waves. Tile: 64 rows x 128 cols.
//   lane (0..63)  -> row within tile
//   wave (0..7)   -> 16-column group
// A staged transposed in LDS with +1 pad: AtT[k][row], conflict-free on both
// staging writes and compute reads. W accessed via readfirstlane-uniform
// pointers -> s_load + SGPR operand in v_fma_f32.
// ---------------------------------------------------------------------------
__global__ __launch_bounds__(512) void gemm_kernel(
    const float* __restrict__ x,
    const float* __restrict__ Wrel,
    const float* __restrict__ Wroot,
    const float* __restrict__ bias,
    float*       out)               // holds agg on entry, result on exit
{
    __shared__ float AtT[128][65];  // [k][row], 65 = 64 rows + pad  (33.3 KB)

    const int tid  = threadIdx.x;
    const int lane = tid & 63;                                   // row in tile
    const int wid  = __builtin_amdgcn_readfirstlane(tid >> 6);   // col group 0..7
    const int row0 = blockIdx.x * 64;
    const int rowg = row0 + lane;

    float acc[16];
    {
        const float* bb = bias + wid * 16;
        #pragma unroll
        for (int c = 0; c < 16; c++) acc[c] = bb[c];
    }

    for (int phase = 0; phase < 2; phase++) {
        const float* A = phase ? x : out;                  // agg lives in out
        const float* W = (phase ? Wroot : Wrel) + wid * 16 * D;

        __syncthreads();   // previous phase done reading AtT
        // stage A tile transposed: coalesced global reads, conflict-free LDS
        #pragma unroll
        for (int i = 0; i < 16; i++) {
            int e = i * 512 + tid;          // 0..8191
            int r = e >> 7, k = e & 127;
            int rg = row0 + r;
            AtT[k][r] = (rg < NN) ? A[rg * D + k] : 0.0f;
        }
        __syncthreads();

        for (int k4 = 0; k4 < 32; k4++) {
            float a0 = AtT[k4 * 4 + 0][lane];
            float a1 = AtT[k4 * 4 + 1][lane];
            float a2 = AtT[k4 * 4 + 2][lane];
            float a3 = AtT[k4 * 4 + 3][lane];
            #pragma unroll
            for (int c = 0; c < 16; c++) {
                const float* wp = W + c * D + k4 * 4;   // uniform -> s_load
                acc[c] += a0 * wp[0] + a1 * wp[1] + a2 * wp[2] + a3 * wp[3];
            }
        }
    }

    // write-back through LDS transpose for coalesced stores
    __syncthreads();
    #pragma unroll
    for (int c = 0; c < 16; c++)
        AtT[wid * 16 + c][lane] = acc[c];   // conflict-free (consecutive lanes)
    __syncthreads();
    #pragma unroll
    for (int i = 0; i < 16; i++) {
        int e = i * 512 + tid;
        int r = e >> 7, col = e & 127;
        int rg = row0 + r;
        if (rg < NN) out[rg * D + col] = AtT[col][r];   // coalesced
    }
}

extern "C" void kernel_launch(void* const* d_in, const int* in_sizes, int n_in,
                              void* d_out, int out_size, void* d_ws, size_t ws_size,
                              hipStream_t stream) {
    const float* x     = (const float*)d_in[0];
    const int*   ei    = (const int*)  d_in[1];
    const float* ew    = (const float*)d_in[2];
    const float* Wrel  = (const float*)d_in[3];
    const float* Wroot = (const float*)d_in[4];
    const float* bias  = (const float*)d_in[5];
    float*       out   = (float*)d_out;

    // agg accumulates in d_out
    hipMemsetAsync(out, 0, (size_t)NN * D * sizeof(float), stream);

    // E*128 threads / 256 per block = 320000 blocks
    scatter_kernel<<<(EE * 128) / 256, 256, 0, stream>>>(x, ei, ew, out);

    gemm_kernel<<<(NN + 63) / 64, 512, 0, stream>>>(x, Wrel, Wroot, bias, out);
}

// Round 2
// 308.834 us; speedup vs baseline: 1.4936x; 1.4936x over previous
//
#include <hip/hip_runtime.h>

#define NN 100000
#define EE 640000
#define D 128
#define NBINS NN
#define SCAN_NBLK 98          // ceil(100000/1024)

// ---------------------------------------------------------------------------
// Workspace layout (ints):
//   cnt      [0      , 100000)   -- histogram (zeroed each call)
//   cursor   [100000 , 200000)   -- slot counters (zeroed each call)
//   offs     [200000 , 300001)   -- CSR offsets (exclusive scan), offs[NN]=E
//   bsum     [300032 , 300160)   -- per-scan-block sums
//   sortedSrc[300160 , 940160)   -- src indices, dst-sorted
//   sortedW  [940160 ,1580160)   -- weights,     dst-sorted
// ---------------------------------------------------------------------------
#define WS_CNT     0
#define WS_CURSOR  100000
#define WS_OFFS    200000
#define WS_BSUM    300032
#define WS_SSRC    300160
#define WS_SW      940160
#define WS_INTS    1580160

// ---- fallback path (atomic scatter), used only if ws too small -------------
__global__ __launch_bounds__(256) void scatter_kernel(
    const float* __restrict__ x, const int* __restrict__ ei,
    const float* __restrict__ ew, float* agg)
{
    int gid = blockIdx.x * 256 + threadIdx.x;
    int e = gid >> 7, f = gid & 127;
    if (e >= EE) return;
    float v = x[ei[e] * D + f] * ew[e];
    unsafeAtomicAdd(&agg[ei[EE + e] * D + f], v);
}

// ---- 1. histogram of dst ---------------------------------------------------
__global__ __launch_bounds__(256) void hist_kernel(
    const int* __restrict__ ei, int* __restrict__ cnt)
{
    int e = blockIdx.x * 256 + threadIdx.x;
    if (e < EE) atomicAdd(&cnt[ei[EE + e]], 1);
}

// ---- 2a. block-level exclusive scan (1024 elems/block) ---------------------
__global__ __launch_bounds__(256) void scanA_kernel(
    const int* __restrict__ cnt, int* __restrict__ offs, int* __restrict__ bsum)
{
    __shared__ int tsum[256];
    const int tid = threadIdx.x;
    const int base = blockIdx.x * 1024 + tid * 4;
    int v[4], s = 0;
    #pragma unroll
    for (int i = 0; i < 4; i++) {
        int idx = base + i;
        v[i] = (idx < NBINS) ? cnt[idx] : 0;
        s += v[i];
    }
    tsum[tid] = s;
    __syncthreads();
    for (int off = 1; off < 256; off <<= 1) {
        int t = (tid >= off) ? tsum[tid - off] : 0;
        __syncthreads();
        tsum[tid] += t;
        __syncthreads();
    }
    int run = tsum[tid] - s;      // exclusive prefix of this thread
    #pragma unroll
    for (int i = 0; i < 4; i++) {
        int idx = base + i;
        if (idx < NBINS) offs[idx] = run;
        run += v[i];
    }
    if (tid == 255) bsum[blockIdx.x] = tsum[255];
}

// ---- 2b. scan the block sums (single block) --------------------------------
__global__ __launch_bounds__(128) void scanB_kernel(int* __restrict__ bsum)
{
    __shared__ int s[128];
    const int tid = threadIdx.x;
    int orig = (tid < SCAN_NBLK) ? bsum[tid] : 0;
    s[tid] = orig;
    __syncthreads();
    for (int off = 1; off < 128; off <<= 1) {
        int t = (tid >= off) ? s[tid - off] : 0;
        __syncthreads();
        s[tid] += t;
        __syncthreads();
    }
    if (tid < SCAN_NBLK) bsum[tid] = s[tid] - orig;
}

// ---- 2c. add block offsets -------------------------------------------------
__global__ __launch_bounds__(256) void scanC_kernel(
    int* __restrict__ offs, const int* __restrict__ bsum)
{
    const int base = blockIdx.x * 1024 + threadIdx.x * 4;
    const int add = bsum[blockIdx.x];
    #pragma unroll
    for (int i = 0; i < 4; i++) {
        int idx = base + i;
        if (idx < NBINS) offs[idx] += add;
    }
    if (blockIdx.x == 0 && threadIdx.x == 0) offs[NBINS] = EE;
}

// ---- 3. permute edges into dst-sorted order --------------------------------
__global__ __launch_bounds__(256) void build_kernel(
    const int* __restrict__ ei, const float* __restrict__ ew,
    const int* __restrict__ offs, int* __restrict__ cursor,
    int* __restrict__ sortedSrc, float* __restrict__ sortedW)
{
    int e = blockIdx.x * 256 + threadIdx.x;
    if (e >= EE) return;
    int dst = ei[EE + e];
    int slot = atomicAdd(&cursor[dst], 1);
    int p = offs[dst] + slot;
    sortedSrc[p] = ei[e];
    sortedW[p]   = ew[e];
}

// ---- 4. gather-aggregate: one wave per node, lane = float2 -----------------
__global__ __launch_bounds__(256) void aggregate_kernel(
    const float* __restrict__ x, const int* __restrict__ offs,
    const int* __restrict__ sortedSrc, const float* __restrict__ sortedW,
    float* __restrict__ out)
{
    const int node = blockIdx.x * 4 + (threadIdx.x >> 6);
    const int lane = threadIdx.x & 63;
    if (node >= NN) return;
    const int beg = offs[node], end = offs[node + 1];
    const float2* x2 = (const float2*)x;
    float ax = 0.f, ay = 0.f;
    int j = beg;
    for (; j + 1 < end; j += 2) {           // 2-deep for load ILP
        int   s0 = sortedSrc[j],   s1 = sortedSrc[j + 1];
        float w0 = sortedW[j],     w1 = sortedW[j + 1];
        float2 v0 = x2[(size_t)s0 * 64 + lane];
        float2 v1 = x2[(size_t)s1 * 64 + lane];
        ax += w0 * v0.x + w1 * v1.x;
        ay += w0 * v0.y + w1 * v1.y;
    }
    if (j < end) {
        int s0 = sortedSrc[j]; float w0 = sortedW[j];
        float2 v0 = x2[(size_t)s0 * 64 + lane];
        ax += w0 * v0.x;
        ay += w0 * v0.y;
    }
    ((float2*)out)[(size_t)node * 64 + lane] = make_float2(ax, ay);
}

// ---- 5. out = agg @ Wrel^T + x @ Wroot^T + b  (in place, agg == out) -------
__global__ __launch_bounds__(512) void gemm_kernel(
    const float* __restrict__ x, const float* __restrict__ Wrel,
    const float* __restrict__ Wroot, const float* __restrict__ bias,
    float* out)
{
    __shared__ float AtT[128][65];

    const int tid  = threadIdx.x;
    const int lane = tid & 63;
    const int wid  = __builtin_amdgcn_readfirstlane(tid >> 6);
    const int row0 = blockIdx.x * 64;

    float acc[16];
    {
        const float* bb = bias + wid * 16;
        #pragma unroll
        for (int c = 0; c < 16; c++) acc[c] = bb[c];
    }

    for (int phase = 0; phase < 2; phase++) {
        const float* A = phase ? x : out;
        const float* W = (phase ? Wroot : Wrel) + wid * 16 * D;

        __syncthreads();
        #pragma unroll
        for (int i = 0; i < 16; i++) {
            int e = i * 512 + tid;
            int r = e >> 7, k = e & 127;
            int rg = row0 + r;
            AtT[k][r] = (rg < NN) ? A[rg * D + k] : 0.0f;
        }
        __syncthreads();

        for (int k4 = 0; k4 < 32; k4++) {
            float a0 = AtT[k4 * 4 + 0][lane];
            float a1 = AtT[k4 * 4 + 1][lane];
            float a2 = AtT[k4 * 4 + 2][lane];
            float a3 = AtT[k4 * 4 + 3][lane];
            #pragma unroll
            for (int c = 0; c < 16; c++) {
                const float* wp = W + c * D + k4 * 4;
                acc[c] += a0 * wp[0] + a1 * wp[1] + a2 * wp[2] + a3 * wp[3];
            }
        }
    }

    __syncthreads();
    #pragma unroll
    for (int c = 0; c < 16; c++)
        AtT[wid * 16 + c][lane] = acc[c];
    __syncthreads();
    #pragma unroll
    for (int i = 0; i < 16; i++) {
        int e = i * 512 + tid;
        int r = e >> 7, col = e & 127;
        int rg = row0 + r;
        if (rg < NN) out[rg * D + col] = AtT[col][r];
    }
}

extern "C" void kernel_launch(void* const* d_in, const int* in_sizes, int n_in,
                              void* d_out, int out_size, void* d_ws, size_t ws_size,
                              hipStream_t stream) {
    const float* x     = (const float*)d_in[0];
    const int*   ei    = (const int*)  d_in[1];
    const float* ew    = (const float*)d_in[2];
    const float* Wrel  = (const float*)d_in[3];
    const float* Wroot = (const float*)d_in[4];
    const float* bias  = (const float*)d_in[5];
    float*       out   = (float*)d_out;

    if (ws_size >= (size_t)WS_INTS * sizeof(int)) {
        int* w = (int*)d_ws;
        int*   cnt       = w + WS_CNT;
        int*   cursor    = w + WS_CURSOR;
        int*   offs      = w + WS_OFFS;
        int*   bsum      = w + WS_BSUM;
        int*   sortedSrc = w + WS_SSRC;
        float* sortedW   = (float*)(w + WS_SW);

        hipMemsetAsync(cnt, 0, 2 * NBINS * sizeof(int), stream);  // cnt+cursor

        const int eb = (EE + 255) / 256;
        hist_kernel <<<eb, 256, 0, stream>>>(ei, cnt);
        scanA_kernel<<<SCAN_NBLK, 256, 0, stream>>>(cnt, offs, bsum);
        scanB_kernel<<<1, 128, 0, stream>>>(bsum);
        scanC_kernel<<<SCAN_NBLK, 256, 0, stream>>>(offs, bsum);
        build_kernel<<<eb, 256, 0, stream>>>(ei, ew, offs, cursor, sortedSrc, sortedW);
        aggregate_kernel<<<(NN + 3) / 4, 256, 0, stream>>>(x, offs, sortedSrc, sortedW, out);
    } else {
        hipMemsetAsync(out, 0, (size_t)NN * D * sizeof(float), stream);
        scatter_kernel<<<(EE * 128) / 256, 256, 0, stream>>>(x, ei, ew, out);
    }

    gemm_kernel<<<(NN + 63) / 64, 512, 0, stream>>>(x, Wrel, Wroot, bias, out);
}

// Round 3
// 184.747 us; speedup vs baseline: 2.4968x; 1.6717x over previous
//
#include <hip/hip_runtime.h>

#define NN 100000
#define EE 640000
#define D 128
#define NBINS NN
#define SCAN_NBLK 98          // ceil(100000/1024)

// ---------------------------------------------------------------------------
// Workspace layout (4-byte units):
//   cnt      [0      , 100000)   histogram (zeroed each call)
//   cursor   [100000 , 200000)   slot counters (zeroed each call)
//   offs     [200000 , 300001)   CSR offsets, offs[NN]=E
//   bsum     [300032 , 300160)   per-scan-block sums
//   sortedSrc[300160 , 940160)   src indices, dst-sorted
//   sortedW  [940160 ,1580160)   weights,     dst-sorted
//   Wb       [1580160,1612928)   W split to bf16: [2][128 c][256 k] shorts
// ---------------------------------------------------------------------------
#define WS_CNT     0
#define WS_CURSOR  100000
#define WS_OFFS    200000
#define WS_BSUM    300032
#define WS_SSRC    300160
#define WS_SW      940160
#define WS_WCONV   1580160
#define WS_INTS    1612928

typedef __attribute__((ext_vector_type(8))) short short8v;
typedef __attribute__((ext_vector_type(4))) float floatx4;

__device__ inline void split_bf16(float f, short& h, short& l) {
    unsigned u  = __float_as_uint(f);
    unsigned hb = u & 0xFFFF0000u;
    h = (short)(u >> 16);
    float fl = f - __uint_as_float(hb);
    l = (short)(__float_as_uint(fl) >> 16);
}

// ---- fallback path (atomic scatter), used only if ws too small -------------
__global__ __launch_bounds__(256) void scatter_kernel(
    const float* __restrict__ x, const int* __restrict__ ei,
    const float* __restrict__ ew, float* agg)
{
    int gid = blockIdx.x * 256 + threadIdx.x;
    int e = gid >> 7, f = gid & 127;
    if (e >= EE) return;
    float v = x[ei[e] * D + f] * ew[e];
    unsafeAtomicAdd(&agg[ei[EE + e] * D + f], v);
}

// ---- 1. histogram of dst ---------------------------------------------------
__global__ __launch_bounds__(256) void hist_kernel(
    const int* __restrict__ ei, int* __restrict__ cnt)
{
    int e = blockIdx.x * 256 + threadIdx.x;
    if (e < EE) atomicAdd(&cnt[ei[EE + e]], 1);
}

// ---- 2a. block-level exclusive scan (1024 elems/block) ---------------------
__global__ __launch_bounds__(256) void scanA_kernel(
    const int* __restrict__ cnt, int* __restrict__ offs, int* __restrict__ bsum)
{
    __shared__ int tsum[256];
    const int tid = threadIdx.x;
    const int base = blockIdx.x * 1024 + tid * 4;
    int v[4], s = 0;
    #pragma unroll
    for (int i = 0; i < 4; i++) {
        int idx = base + i;
        v[i] = (idx < NBINS) ? cnt[idx] : 0;
        s += v[i];
    }
    tsum[tid] = s;
    __syncthreads();
    for (int off = 1; off < 256; off <<= 1) {
        int t = (tid >= off) ? tsum[tid - off] : 0;
        __syncthreads();
        tsum[tid] += t;
        __syncthreads();
    }
    int run = tsum[tid] - s;
    #pragma unroll
    for (int i = 0; i < 4; i++) {
        int idx = base + i;
        if (idx < NBINS) offs[idx] = run;
        run += v[i];
    }
    if (tid == 255) bsum[blockIdx.x] = tsum[255];
}

// ---- 2b. scan the block sums (single block) --------------------------------
__global__ __launch_bounds__(128) void scanB_kernel(int* __restrict__ bsum)
{
    __shared__ int s[128];
    const int tid = threadIdx.x;
    int orig = (tid < SCAN_NBLK) ? bsum[tid] : 0;
    s[tid] = orig;
    __syncthreads();
    for (int off = 1; off < 128; off <<= 1) {
        int t = (tid >= off) ? s[tid - off] : 0;
        __syncthreads();
        s[tid] += t;
        __syncthreads();
    }
    if (tid < SCAN_NBLK) bsum[tid] = s[tid] - orig;
}

// ---- 2c. add block offsets -------------------------------------------------
__global__ __launch_bounds__(256) void scanC_kernel(
    int* __restrict__ offs, const int* __restrict__ bsum)
{
    const int base = blockIdx.x * 1024 + threadIdx.x * 4;
    const int add = bsum[blockIdx.x];
    #pragma unroll
    for (int i = 0; i < 4; i++) {
        int idx = base + i;
        if (idx < NBINS) offs[idx] += add;
    }
    if (blockIdx.x == 0 && threadIdx.x == 0) offs[NBINS] = EE;
}

// ---- 3. permute edges into dst-sorted order --------------------------------
__global__ __launch_bounds__(256) void build_kernel(
    const int* __restrict__ ei, const float* __restrict__ ew,
    const int* __restrict__ offs, int* __restrict__ cursor,
    int* __restrict__ sortedSrc, float* __restrict__ sortedW)
{
    int e = blockIdx.x * 256 + threadIdx.x;
    if (e >= EE) return;
    int dst = ei[EE + e];
    int slot = atomicAdd(&cursor[dst], 1);
    int p = offs[dst] + slot;
    sortedSrc[p] = ei[e];
    sortedW[p]   = ew[e];
}

// ---- 4. gather-aggregate: one wave per node, lane = float2 -----------------
__global__ __launch_bounds__(256) void aggregate_kernel(
    const float* __restrict__ x, const int* __restrict__ offs,
    const int* __restrict__ sortedSrc, const float* __restrict__ sortedW,
    float* __restrict__ out)
{
    const int node = blockIdx.x * 4 + (threadIdx.x >> 6);
    const int lane = threadIdx.x & 63;
    if (node >= NN) return;
    const int beg = offs[node], end = offs[node + 1];
    const float2* x2 = (const float2*)x;
    float ax = 0.f, ay = 0.f;
    int j = beg;
    for (; j + 1 < end; j += 2) {
        int   s0 = sortedSrc[j],   s1 = sortedSrc[j + 1];
        float w0 = sortedW[j],     w1 = sortedW[j + 1];
        float2 v0 = x2[(size_t)s0 * 64 + lane];
        float2 v1 = x2[(size_t)s1 * 64 + lane];
        ax += w0 * v0.x + w1 * v1.x;
        ay += w0 * v0.y + w1 * v1.y;
    }
    if (j < end) {
        int s0 = sortedSrc[j]; float w0 = sortedW[j];
        float2 v0 = x2[(size_t)s0 * 64 + lane];
        ax += w0 * v0.x;
        ay += w0 * v0.y;
    }
    ((float2*)out)[(size_t)node * 64 + lane] = make_float2(ax, ay);
}

// ---- 5a. pre-split W into bf16 hi/lo: Wb[2][128 c][256 k] ------------------
__global__ __launch_bounds__(256) void wconv_kernel(
    const float* __restrict__ Wrel, const float* __restrict__ Wroot,
    short* __restrict__ Wb)
{
    int i = blockIdx.x * 256 + threadIdx.x;   // 0..32767
    int c = i >> 8, k = i & 255;
    float f = (k < 128) ? Wrel[c * 128 + k] : Wroot[c * 128 + (k - 128)];
    short h, l;
    split_bf16(f, h, l);
    Wb[i] = h;
    Wb[32768 + i] = l;
}

// ---- 5b. MFMA GEMM: out = [agg|x] @ [Wrel;Wroot]^T + b  (split-bf16, 3-term)
// Block: 256 thr = 4 waves, tile 128 rows x 128 cols, K = 256 in 4 chunks.
// Wave w owns rows [w*32, w*32+32). LDS tiles [128][64] bf16 with 16B-block
// XOR swizzle: elem idx(r,k) = r*64 + (((k>>3)^(r&7))<<3) + (k&7).
// agg lives in `out`; block reads only its own rows, writes after full K loop.
__global__ __launch_bounds__(256) void mfma_gemm_kernel(
    const float* __restrict__ x, const short* __restrict__ Wb,
    const float* __restrict__ bias, float* __restrict__ out)
{
    __shared__ short lds[4 * 128 * 64];   // Ah, Al, Wh, Wl : 64 KB
    short* Ah = lds;
    short* Al = lds + 8192;
    short* Wh = lds + 16384;
    short* Wl = lds + 24576;

    const int tid  = threadIdx.x;
    const int lane = tid & 63;
    const int wave = tid >> 6;
    const int row0 = blockIdx.x * 128;
    const int frow = lane & 15;          // m (or n) index within fragment
    const int fk   = (lane >> 4) * 8;    // k sub-offset within 32-wide K slice

    floatx4 acc[2][8];
    #pragma unroll
    for (int nf = 0; nf < 8; nf++) {
        float b = bias[nf * 16 + frow];
        #pragma unroll
        for (int mf = 0; mf < 2; mf++) acc[mf][nf] = (floatx4){b, b, b, b};
    }

    for (int kc = 0; kc < 4; kc++) {
        const float* A = (kc < 2) ? out : x;     // K<128 -> agg (in out)
        const int kcol = (kc & 1) * 64;
        __syncthreads();
        // stage A tile: 8192 f32 -> hi/lo bf16, swizzled
        #pragma unroll
        for (int i = 0; i < 8; i++) {
            int e = (i * 256 + tid) * 4;
            int r = e >> 6, k = e & 63;
            int rg = row0 + r;
            float4 v = (rg < NN) ? *(const float4*)&A[(size_t)rg * D + kcol + k]
                                 : make_float4(0.f, 0.f, 0.f, 0.f);
            short4 h, l;
            split_bf16(v.x, h.x, l.x);
            split_bf16(v.y, h.y, l.y);
            split_bf16(v.z, h.z, l.z);
            split_bf16(v.w, h.w, l.w);
            int sidx = r * 64 + (((k >> 3) ^ (r & 7)) << 3) + (k & 7);
            *(short4*)&Ah[sidx] = h;
            *(short4*)&Al[sidx] = l;
        }
        // stage W tile: copy pre-split bf16, swizzled
        #pragma unroll
        for (int i = 0; i < 4; i++) {
            int e = (i * 256 + tid) * 8;
            int c = e >> 6, k = e & 63;
            int sidx = c * 64 + (((k >> 3) ^ (c & 7)) << 3);
            int g = c * 256 + kc * 64 + k;
            *(short8v*)&Wh[sidx] = *(const short8v*)&Wb[g];
            *(short8v*)&Wl[sidx] = *(const short8v*)&Wb[32768 + g];
        }
        __syncthreads();

        const int arow = wave * 32;
        #pragma unroll
        for (int kf = 0; kf < 2; kf++) {
            const int k0 = kf * 32 + fk;
            const int kblk = k0 >> 3;
            short8v ah[2], al[2];
            #pragma unroll
            for (int mf = 0; mf < 2; mf++) {
                int r = arow + mf * 16 + frow;
                int idx = r * 64 + ((kblk ^ (r & 7)) << 3);
                ah[mf] = *(const short8v*)&Ah[idx];
                al[mf] = *(const short8v*)&Al[idx];
            }
            #pragma unroll
            for (int nf = 0; nf < 8; nf++) {
                int cc = nf * 16 + frow;
                int idx = cc * 64 + ((kblk ^ (cc & 7)) << 3);
                short8v bh = *(const short8v*)&Wh[idx];
                short8v bl = *(const short8v*)&Wl[idx];
                #pragma unroll
                for (int mf = 0; mf < 2; mf++) {
                    acc[mf][nf] = __builtin_amdgcn_mfma_f32_16x16x32_bf16(ah[mf], bh, acc[mf][nf], 0, 0, 0);
                    acc[mf][nf] = __builtin_amdgcn_mfma_f32_16x16x32_bf16(al[mf], bh, acc[mf][nf], 0, 0, 0);
                    acc[mf][nf] = __builtin_amdgcn_mfma_f32_16x16x32_bf16(ah[mf], bl, acc[mf][nf], 0, 0, 0);
                }
            }
        }
    }

    // write-back: C/D layout col=lane&15, row=(lane>>4)*4+reg  [m89-verified]
    const int orow = row0 + wave * 32;
    #pragma unroll
    for (int mf = 0; mf < 2; mf++) {
        #pragma unroll
        for (int j = 0; j < 4; j++) {
            int r = orow + mf * 16 + (lane >> 4) * 4 + j;
            if (r < NN) {
                #pragma unroll
                for (int nf = 0; nf < 8; nf++)
                    out[(size_t)r * D + nf * 16 + (lane & 15)] = acc[mf][nf][j];
            }
        }
    }
}

// ---- fallback fp32 GEMM (only if ws too small) -----------------------------
__global__ __launch_bounds__(512) void gemm_kernel(
    const float* __restrict__ x, const float* __restrict__ Wrel,
    const float* __restrict__ Wroot, const float* __restrict__ bias,
    float* out)
{
    __shared__ float AtT[128][65];
    const int tid  = threadIdx.x;
    const int lane = tid & 63;
    const int wid  = __builtin_amdgcn_readfirstlane(tid >> 6);
    const int row0 = blockIdx.x * 64;
    float acc[16];
    {
        const float* bb = bias + wid * 16;
        #pragma unroll
        for (int c = 0; c < 16; c++) acc[c] = bb[c];
    }
    for (int phase = 0; phase < 2; phase++) {
        const float* A = phase ? x : out;
        const float* W = (phase ? Wroot : Wrel) + wid * 16 * D;
        __syncthreads();
        #pragma unroll
        for (int i = 0; i < 16; i++) {
            int e = i * 512 + tid;
            int r = e >> 7, k = e & 127;
            int rg = row0 + r;
            AtT[k][r] = (rg < NN) ? A[rg * D + k] : 0.0f;
        }
        __syncthreads();
        for (int k4 = 0; k4 < 32; k4++) {
            float a0 = AtT[k4 * 4 + 0][lane];
            float a1 = AtT[k4 * 4 + 1][lane];
            float a2 = AtT[k4 * 4 + 2][lane];
            float a3 = AtT[k4 * 4 + 3][lane];
            #pragma unroll
            for (int c = 0; c < 16; c++) {
                const float* wp = W + c * D + k4 * 4;
                acc[c] += a0 * wp[0] + a1 * wp[1] + a2 * wp[2] + a3 * wp[3];
            }
        }
    }
    __syncthreads();
    #pragma unroll
    for (int c = 0; c < 16; c++)
        AtT[wid * 16 + c][lane] = acc[c];
    __syncthreads();
    #pragma unroll
    for (int i = 0; i < 16; i++) {
        int e = i * 512 + tid;
        int r = e >> 7, col = e & 127;
        int rg = row0 + r;
        if (rg < NN) out[rg * D + col] = AtT[col][r];
    }
}

extern "C" void kernel_launch(void* const* d_in, const int* in_sizes, int n_in,
                              void* d_out, int out_size, void* d_ws, size_t ws_size,
                              hipStream_t stream) {
    const float* x     = (const float*)d_in[0];
    const int*   ei    = (const int*)  d_in[1];
    const float* ew    = (const float*)d_in[2];
    const float* Wrel  = (const float*)d_in[3];
    const float* Wroot = (const float*)d_in[4];
    const float* bias  = (const float*)d_in[5];
    float*       out   = (float*)d_out;

    if (ws_size >= (size_t)WS_INTS * sizeof(int)) {
        int* w = (int*)d_ws;
        int*   cnt       = w + WS_CNT;
        int*   cursor    = w + WS_CURSOR;
        int*   offs      = w + WS_OFFS;
        int*   bsum      = w + WS_BSUM;
        int*   sortedSrc = w + WS_SSRC;
        float* sortedW   = (float*)(w + WS_SW);
        short* Wb        = (short*)(w + WS_WCONV);

        hipMemsetAsync(cnt, 0, 2 * NBINS * sizeof(int), stream);  // cnt+cursor

        const int eb = (EE + 255) / 256;
        wconv_kernel<<<128, 256, 0, stream>>>(Wrel, Wroot, Wb);
        hist_kernel <<<eb, 256, 0, stream>>>(ei, cnt);
        scanA_kernel<<<SCAN_NBLK, 256, 0, stream>>>(cnt, offs, bsum);
        scanB_kernel<<<1, 128, 0, stream>>>(bsum);
        scanC_kernel<<<SCAN_NBLK, 256, 0, stream>>>(offs, bsum);
        build_kernel<<<eb, 256, 0, stream>>>(ei, ew, offs, cursor, sortedSrc, sortedW);
        aggregate_kernel<<<(NN + 3) / 4, 256, 0, stream>>>(x, offs, sortedSrc, sortedW, out);
        mfma_gemm_kernel<<<(NN + 127) / 128, 256, 0, stream>>>(x, Wb, bias, out);
    } else {
        hipMemsetAsync(out, 0, (size_t)NN * D * sizeof(float), stream);
        scatter_kernel<<<(EE * 128) / 256, 256, 0, stream>>>(x, ei, ew, out);
        gemm_kernel<<<(NN + 63) / 64, 512, 0, stream>>>(x, Wrel, Wroot, bias, out);
    }
}

// Round 4
// 169.894 us; speedup vs baseline: 2.7150x; 1.0874x over previous
//
#include <hip/hip_runtime.h>

#define NN 100000
#define EE 640000
#define D 128
#define NBINS NN
#define SCAN_NBLK 98          // ceil(100000/1024)

// ---------------------------------------------------------------------------
// Workspace layout (4-byte units):
//   cnt  [0      , 100000)    histogram (zeroed each call)
//   offs [100000 , 200000)    exclusive scan; build mutates to inclusive-end
//   bsum [200000 , 200128)    per-scan-block sums
//   sw   [200192 , 1480192)   packed (src, w) int2, dst-sorted   (8B aligned)
//   Wb   [1480192, 1512960)   W split to bf16: [2][128 c][256 k] shorts
// ---------------------------------------------------------------------------
#define WS_CNT     0
#define WS_OFFS    100000
#define WS_BSUM    200000
#define WS_SW      200192
#define WS_WCONV   1480192
#define WS_INTS    1512960

typedef __attribute__((ext_vector_type(8))) short short8v;
typedef __attribute__((ext_vector_type(4))) float floatx4;

__device__ inline void split_bf16(float f, short& h, short& l) {
    unsigned u  = __float_as_uint(f);
    unsigned hb = u & 0xFFFF0000u;
    h = (short)(u >> 16);
    float fl = f - __uint_as_float(hb);
    l = (short)(__float_as_uint(fl) >> 16);
}

// ---- fallback path (atomic scatter), used only if ws too small -------------
__global__ __launch_bounds__(256) void scatter_kernel(
    const float* __restrict__ x, const int* __restrict__ ei,
    const float* __restrict__ ew, float* agg)
{
    int gid = blockIdx.x * 256 + threadIdx.x;
    int e = gid >> 7, f = gid & 127;
    if (e >= EE) return;
    float v = x[ei[e] * D + f] * ew[e];
    unsafeAtomicAdd(&agg[ei[EE + e] * D + f], v);
}

// ---- 1. histogram of dst ---------------------------------------------------
__global__ __launch_bounds__(256) void hist_kernel(
    const int* __restrict__ ei, int* __restrict__ cnt)
{
    int e = blockIdx.x * 256 + threadIdx.x;
    if (e < EE) atomicAdd(&cnt[ei[EE + e]], 1);
}

// ---- 2a. block-level exclusive scan (1024 elems/block) ---------------------
__global__ __launch_bounds__(256) void scanA_kernel(
    const int* __restrict__ cnt, int* __restrict__ offs, int* __restrict__ bsum)
{
    __shared__ int tsum[256];
    const int tid = threadIdx.x;
    const int base = blockIdx.x * 1024 + tid * 4;
    int v[4], s = 0;
    #pragma unroll
    for (int i = 0; i < 4; i++) {
        int idx = base + i;
        v[i] = (idx < NBINS) ? cnt[idx] : 0;
        s += v[i];
    }
    tsum[tid] = s;
    __syncthreads();
    for (int off = 1; off < 256; off <<= 1) {
        int t = (tid >= off) ? tsum[tid - off] : 0;
        __syncthreads();
        tsum[tid] += t;
        __syncthreads();
    }
    int run = tsum[tid] - s;
    #pragma unroll
    for (int i = 0; i < 4; i++) {
        int idx = base + i;
        if (idx < NBINS) offs[idx] = run;
        run += v[i];
    }
    if (tid == 255) bsum[blockIdx.x] = tsum[255];
}

// ---- 2b. fused: every block scans bsum in LDS, adds its prefix -------------
__global__ __launch_bounds__(256) void scanC_kernel(
    int* __restrict__ offs, const int* __restrict__ bsum)
{
    __shared__ int s[128];
    const int tid = threadIdx.x;
    if (tid < 128) s[tid] = (tid < SCAN_NBLK) ? bsum[tid] : 0;
    __syncthreads();
    for (int off = 1; off < 128; off <<= 1) {
        int t = 0;
        if (tid < 128 && tid >= off) t = s[tid - off];
        __syncthreads();
        if (tid < 128) s[tid] += t;
        __syncthreads();
    }
    const int add = (blockIdx.x == 0) ? 0 : s[blockIdx.x - 1];
    const int base = blockIdx.x * 1024 + tid * 4;
    #pragma unroll
    for (int i = 0; i < 4; i++) {
        int idx = base + i;
        if (idx < NBINS) offs[idx] += add;
    }
}

// ---- 3. permute edges into dst-sorted order (offs -> inclusive ends) -------
__global__ __launch_bounds__(256) void build_kernel(
    const int* __restrict__ ei, const float* __restrict__ ew,
    int* __restrict__ offs, int2* __restrict__ sw)
{
    int e = blockIdx.x * 256 + threadIdx.x;
    if (e >= EE) return;
    int dst = ei[EE + e];
    int p = atomicAdd(&offs[dst], 1);          // returns original offset+slot
    sw[p] = make_int2(ei[e], __float_as_int(ew[e]));
}

// ---- 4. gather-aggregate: half-wave (32 lanes x float4) per node -----------
__global__ __launch_bounds__(256) void aggregate_kernel(
    const float* __restrict__ x, const int* __restrict__ offs,
    const int2* __restrict__ sw, float* __restrict__ out)
{
    const int node = blockIdx.x * 8 + (threadIdx.x >> 5);
    const int fl   = threadIdx.x & 31;
    if (node >= NN) return;
    const int beg = (node == 0) ? 0 : offs[node - 1];   // post-build semantics
    const int end = offs[node];
    const float4* x4 = (const float4*)x;

    float4 a0 = make_float4(0.f, 0.f, 0.f, 0.f);
    float4 a1 = make_float4(0.f, 0.f, 0.f, 0.f);
    int j = beg;
    for (; j + 1 < end; j += 2) {
        int2 s0 = sw[j];
        int2 s1 = sw[j + 1];
        float4 v0 = x4[(size_t)s0.x * 32 + fl];
        float4 v1 = x4[(size_t)s1.x * 32 + fl];
        float w0 = __int_as_float(s0.y), w1 = __int_as_float(s1.y);
        a0.x += w0 * v0.x; a0.y += w0 * v0.y; a0.z += w0 * v0.z; a0.w += w0 * v0.w;
        a1.x += w1 * v1.x; a1.y += w1 * v1.y; a1.z += w1 * v1.z; a1.w += w1 * v1.w;
    }
    if (j < end) {
        int2 s0 = sw[j];
        float4 v0 = x4[(size_t)s0.x * 32 + fl];
        float w0 = __int_as_float(s0.y);
        a0.x += w0 * v0.x; a0.y += w0 * v0.y; a0.z += w0 * v0.z; a0.w += w0 * v0.w;
    }
    float4 r = make_float4(a0.x + a1.x, a0.y + a1.y, a0.z + a1.z, a0.w + a1.w);
    ((float4*)out)[(size_t)node * 32 + fl] = r;
}

// ---- 5a. pre-split W into bf16 hi/lo: Wb[2][128 c][256 k] ------------------
__global__ __launch_bounds__(256) void wconv_kernel(
    const float* __restrict__ Wrel, const float* __restrict__ Wroot,
    short* __restrict__ Wb)
{
    int i = blockIdx.x * 256 + threadIdx.x;   // 0..32767
    int c = i >> 8, k = i & 255;
    float f = (k < 128) ? Wrel[c * 128 + k] : Wroot[c * 128 + (k - 128)];
    short h, l;
    split_bf16(f, h, l);
    Wb[i] = h;
    Wb[32768 + i] = l;
}

// ---- 5b. MFMA GEMM: out = [agg|x] @ [Wrel;Wroot]^T + b  (split-bf16, 3-term)
__global__ __launch_bounds__(256) void mfma_gemm_kernel(
    const float* __restrict__ x, const short* __restrict__ Wb,
    const float* __restrict__ bias, float* __restrict__ out)
{
    __shared__ short lds[4 * 128 * 64];   // Ah, Al, Wh, Wl : 64 KB
    short* Ah = lds;
    short* Al = lds + 8192;
    short* Wh = lds + 16384;
    short* Wl = lds + 24576;

    const int tid  = threadIdx.x;
    const int lane = tid & 63;
    const int wave = tid >> 6;
    const int row0 = blockIdx.x * 128;
    const int frow = lane & 15;
    const int fk   = (lane >> 4) * 8;

    floatx4 acc[2][8];
    #pragma unroll
    for (int nf = 0; nf < 8; nf++) {
        float b = bias[nf * 16 + frow];
        #pragma unroll
        for (int mf = 0; mf < 2; mf++) acc[mf][nf] = (floatx4){b, b, b, b};
    }

    for (int kc = 0; kc < 4; kc++) {
        const float* A = (kc < 2) ? out : x;     // K<128 -> agg (in out)
        const int kcol = (kc & 1) * 64;
        __syncthreads();
        #pragma unroll
        for (int i = 0; i < 8; i++) {
            int e = (i * 256 + tid) * 4;
            int r = e >> 6, k = e & 63;
            int rg = row0 + r;
            float4 v = (rg < NN) ? *(const float4*)&A[(size_t)rg * D + kcol + k]
                                 : make_float4(0.f, 0.f, 0.f, 0.f);
            short4 h, l;
            split_bf16(v.x, h.x, l.x);
            split_bf16(v.y, h.y, l.y);
            split_bf16(v.z, h.z, l.z);
            split_bf16(v.w, h.w, l.w);
            int sidx = r * 64 + (((k >> 3) ^ (r & 7)) << 3) + (k & 7);
            *(short4*)&Ah[sidx] = h;
            *(short4*)&Al[sidx] = l;
        }
        #pragma unroll
        for (int i = 0; i < 4; i++) {
            int e = (i * 256 + tid) * 8;
            int c = e >> 6, k = e & 63;
            int sidx = c * 64 + (((k >> 3) ^ (c & 7)) << 3);
            int g = c * 256 + kc * 64 + k;
            *(short8v*)&Wh[sidx] = *(const short8v*)&Wb[g];
            *(short8v*)&Wl[sidx] = *(const short8v*)&Wb[32768 + g];
        }
        __syncthreads();

        const int arow = wave * 32;
        #pragma unroll
        for (int kf = 0; kf < 2; kf++) {
            const int k0 = kf * 32 + fk;
            const int kblk = k0 >> 3;
            short8v ah[2], al[2];
            #pragma unroll
            for (int mf = 0; mf < 2; mf++) {
                int r = arow + mf * 16 + frow;
                int idx = r * 64 + ((kblk ^ (r & 7)) << 3);
                ah[mf] = *(const short8v*)&Ah[idx];
                al[mf] = *(const short8v*)&Al[idx];
            }
            #pragma unroll
            for (int nf = 0; nf < 8; nf++) {
                int cc = nf * 16 + frow;
                int idx = cc * 64 + ((kblk ^ (cc & 7)) << 3);
                short8v bh = *(const short8v*)&Wh[idx];
                short8v bl = *(const short8v*)&Wl[idx];
                #pragma unroll
                for (int mf = 0; mf < 2; mf++) {
                    acc[mf][nf] = __builtin_amdgcn_mfma_f32_16x16x32_bf16(ah[mf], bh, acc[mf][nf], 0, 0, 0);
                    acc[mf][nf] = __builtin_amdgcn_mfma_f32_16x16x32_bf16(al[mf], bh, acc[mf][nf], 0, 0, 0);
                    acc[mf][nf] = __builtin_amdgcn_mfma_f32_16x16x32_bf16(ah[mf], bl, acc[mf][nf], 0, 0, 0);
                }
            }
        }
    }

    const int orow = row0 + wave * 32;
    #pragma unroll
    for (int mf = 0; mf < 2; mf++) {
        #pragma unroll
        for (int j = 0; j < 4; j++) {
            int r = orow + mf * 16 + (lane >> 4) * 4 + j;
            if (r < NN) {
                #pragma unroll
                for (int nf = 0; nf < 8; nf++)
                    out[(size_t)r * D + nf * 16 + (lane & 15)] = acc[mf][nf][j];
            }
        }
    }
}

// ---- fallback fp32 GEMM (only if ws too small) -----------------------------
__global__ __launch_bounds__(512) void gemm_kernel(
    const float* __restrict__ x, const float* __restrict__ Wrel,
    const float* __restrict__ Wroot, const float* __restrict__ bias,
    float* out)
{
    __shared__ float AtT[128][65];
    const int tid  = threadIdx.x;
    const int lane = tid & 63;
    const int wid  = __builtin_amdgcn_readfirstlane(tid >> 6);
    const int row0 = blockIdx.x * 64;
    float acc[16];
    {
        const float* bb = bias + wid * 16;
        #pragma unroll
        for (int c = 0; c < 16; c++) acc[c] = bb[c];
    }
    for (int phase = 0; phase < 2; phase++) {
        const float* A = phase ? x : out;
        const float* W = (phase ? Wroot : Wrel) + wid * 16 * D;
        __syncthreads();
        #pragma unroll
        for (int i = 0; i < 16; i++) {
            int e = i * 512 + tid;
            int r = e >> 7, k = e & 127;
            int rg = row0 + r;
            AtT[k][r] = (rg < NN) ? A[rg * D + k] : 0.0f;
        }
        __syncthreads();
        for (int k4 = 0; k4 < 32; k4++) {
            float a0 = AtT[k4 * 4 + 0][lane];
            float a1 = AtT[k4 * 4 + 1][lane];
            float a2 = AtT[k4 * 4 + 2][lane];
            float a3 = AtT[k4 * 4 + 3][lane];
            #pragma unroll
            for (int c = 0; c < 16; c++) {
                const float* wp = W + c * D + k4 * 4;
                acc[c] += a0 * wp[0] + a1 * wp[1] + a2 * wp[2] + a3 * wp[3];
            }
        }
    }
    __syncthreads();
    #pragma unroll
    for (int c = 0; c < 16; c++)
        AtT[wid * 16 + c][lane] = acc[c];
    __syncthreads();
    #pragma unroll
    for (int i = 0; i < 16; i++) {
        int e = i * 512 + tid;
        int r = e >> 7, col = e & 127;
        int rg = row0 + r;
        if (rg < NN) out[rg * D + col] = AtT[col][r];
    }
}

extern "C" void kernel_launch(void* const* d_in, const int* in_sizes, int n_in,
                              void* d_out, int out_size, void* d_ws, size_t ws_size,
                              hipStream_t stream) {
    const float* x     = (const float*)d_in[0];
    const int*   ei    = (const int*)  d_in[1];
    const float* ew    = (const float*)d_in[2];
    const float* Wrel  = (const float*)d_in[3];
    const float* Wroot = (const float*)d_in[4];
    const float* bias  = (const float*)d_in[5];
    float*       out   = (float*)d_out;

    if (ws_size >= (size_t)WS_INTS * sizeof(int)) {
        int* w = (int*)d_ws;
        int*   cnt  = w + WS_CNT;
        int*   offs = w + WS_OFFS;
        int*   bsum = w + WS_BSUM;
        int2*  sw   = (int2*)(w + WS_SW);
        short* Wb   = (short*)(w + WS_WCONV);

        hipMemsetAsync(cnt, 0, NBINS * sizeof(int), stream);

        const int eb = (EE + 255) / 256;
        wconv_kernel<<<128, 256, 0, stream>>>(Wrel, Wroot, Wb);
        hist_kernel <<<eb, 256, 0, stream>>>(ei, cnt);
        scanA_kernel<<<SCAN_NBLK, 256, 0, stream>>>(cnt, offs, bsum);
        scanC_kernel<<<SCAN_NBLK, 256, 0, stream>>>(offs, bsum);
        build_kernel<<<eb, 256, 0, stream>>>(ei, ew, offs, sw);
        aggregate_kernel<<<NN / 8, 256, 0, stream>>>(x, offs, sw, out);
        mfma_gemm_kernel<<<(NN + 127) / 128, 256, 0, stream>>>(x, Wb, bias, out);
    } else {
        hipMemsetAsync(out, 0, (size_t)NN * D * sizeof(float), stream);
        scatter_kernel<<<(EE * 128) / 256, 256, 0, stream>>>(x, ei, ew, out);
        gemm_kernel<<<(NN + 63) / 64, 512, 0, stream>>>(x, Wrel, Wroot, bias, out);
    }
}

// Round 5
// 161.102 us; speedup vs baseline: 2.8632x; 1.0546x over previous
//
#include <hip/hip_runtime.h>
#include <hip/hip_fp16.h>

#define NN 100000
#define EE 640000
#define D 128
#define NBINS NN
#define SCAN_NBLK 98          // ceil(100000/1024)

// ---------------------------------------------------------------------------
// Workspace layout (4-byte units):
//   cnt  [0      , 100000)    histogram (zeroed each call)
//   offs [100000 , 200000)    exclusive scan; build mutates to inclusive-end
//   bsum [200000 , 200128)    per-scan-block sums
//   sw   [200192 , 1480192)   packed (src, w) int2, dst-sorted
//   Wb   [1480192, 1512960)   W split to bf16: [2][128 c][256 k] shorts
//   xh   [1512960, 7912960)   x as fp16 [100000][128]          (top tier only)
// ---------------------------------------------------------------------------
#define WS_CNT     0
#define WS_OFFS    100000
#define WS_BSUM    200000
#define WS_SW      200192
#define WS_WCONV   1480192
#define WS_XH      1512960
#define WS_INTS_MID 1512960
#define WS_INTS_TOP 7912960

// prep_kernel block partition
#define PREP_XB 6250          // x->fp16 : 6250*256*8  = 12.8M elems
#define PREP_WB 128           // W split : 128*256     = 32768 elems
#define PREP_HB 2500          // hist    : 2500*256    = 640K edges

typedef __attribute__((ext_vector_type(8))) short short8v;
typedef __attribute__((ext_vector_type(4))) float floatx4;
struct __align__(8) half4t { __half2 a, b; };

__device__ inline void split_bf16(float f, short& h, short& l) {
    unsigned u  = __float_as_uint(f);
    unsigned hb = u & 0xFFFF0000u;
    h = (short)(u >> 16);
    float fl = f - __uint_as_float(hb);
    l = (short)(__float_as_uint(fl) >> 16);
}

// ---- fallback path (atomic scatter), used only if ws tiny ------------------
__global__ __launch_bounds__(256) void scatter_kernel(
    const float* __restrict__ x, const int* __restrict__ ei,
    const float* __restrict__ ew, float* agg)
{
    int gid = blockIdx.x * 256 + threadIdx.x;
    int e = gid >> 7, f = gid & 127;
    if (e >= EE) return;
    float v = x[ei[e] * D + f] * ew[e];
    unsafeAtomicAdd(&agg[ei[EE + e] * D + f], v);
}

// ---- fused prep: x->fp16 | W->split-bf16 | dst histogram -------------------
__global__ __launch_bounds__(256) void prep_kernel(
    const float* __restrict__ x, const float* __restrict__ Wrel,
    const float* __restrict__ Wroot, const int* __restrict__ ei,
    short* __restrict__ xh, short* __restrict__ Wb, int* __restrict__ cnt)
{
    const int b = blockIdx.x;
    if (b < PREP_XB) {
        int i = (b * 256 + threadIdx.x) * 8;
        float4 v0 = *(const float4*)&x[i];
        float4 v1 = *(const float4*)&x[i + 4];
        short8v hv;
        hv[0] = (short)__half_as_ushort(__float2half(v0.x));
        hv[1] = (short)__half_as_ushort(__float2half(v0.y));
        hv[2] = (short)__half_as_ushort(__float2half(v0.z));
        hv[3] = (short)__half_as_ushort(__float2half(v0.w));
        hv[4] = (short)__half_as_ushort(__float2half(v1.x));
        hv[5] = (short)__half_as_ushort(__float2half(v1.y));
        hv[6] = (short)__half_as_ushort(__float2half(v1.z));
        hv[7] = (short)__half_as_ushort(__float2half(v1.w));
        *(short8v*)&xh[i] = hv;
    } else if (b < PREP_XB + PREP_WB) {
        int i = (b - PREP_XB) * 256 + threadIdx.x;   // 0..32767
        int c = i >> 8, k = i & 255;
        float f = (k < 128) ? Wrel[c * 128 + k] : Wroot[c * 128 + (k - 128)];
        short h, l;
        split_bf16(f, h, l);
        Wb[i] = h;
        Wb[32768 + i] = l;
    } else {
        int e = (b - PREP_XB - PREP_WB) * 256 + threadIdx.x;
        if (e < EE) atomicAdd(&cnt[ei[EE + e]], 1);
    }
}

// ---- standalone hist (mid tier) --------------------------------------------
__global__ __launch_bounds__(256) void hist_kernel(
    const int* __restrict__ ei, int* __restrict__ cnt)
{
    int e = blockIdx.x * 256 + threadIdx.x;
    if (e < EE) atomicAdd(&cnt[ei[EE + e]], 1);
}

// ---- standalone wconv (mid tier) -------------------------------------------
__global__ __launch_bounds__(256) void wconv_kernel(
    const float* __restrict__ Wrel, const float* __restrict__ Wroot,
    short* __restrict__ Wb)
{
    int i = blockIdx.x * 256 + threadIdx.x;
    int c = i >> 8, k = i & 255;
    float f = (k < 128) ? Wrel[c * 128 + k] : Wroot[c * 128 + (k - 128)];
    short h, l;
    split_bf16(f, h, l);
    Wb[i] = h;
    Wb[32768 + i] = l;
}

// ---- scanA: block-level exclusive scan (1024 elems/block) ------------------
__global__ __launch_bounds__(256) void scanA_kernel(
    const int* __restrict__ cnt, int* __restrict__ offs, int* __restrict__ bsum)
{
    __shared__ int tsum[256];
    const int tid = threadIdx.x;
    const int base = blockIdx.x * 1024 + tid * 4;
    int v[4], s = 0;
    #pragma unroll
    for (int i = 0; i < 4; i++) {
        int idx = base + i;
        v[i] = (idx < NBINS) ? cnt[idx] : 0;
        s += v[i];
    }
    tsum[tid] = s;
    __syncthreads();
    for (int off = 1; off < 256; off <<= 1) {
        int t = (tid >= off) ? tsum[tid - off] : 0;
        __syncthreads();
        tsum[tid] += t;
        __syncthreads();
    }
    int run = tsum[tid] - s;
    #pragma unroll
    for (int i = 0; i < 4; i++) {
        int idx = base + i;
        if (idx < NBINS) offs[idx] = run;
        run += v[i];
    }
    if (tid == 255) bsum[blockIdx.x] = tsum[255];
}

// ---- scanC: every block scans bsum in LDS, adds its prefix -----------------
__global__ __launch_bounds__(256) void scanC_kernel(
    int* __restrict__ offs, const int* __restrict__ bsum)
{
    __shared__ int s[128];
    const int tid = threadIdx.x;
    if (tid < 128) s[tid] = (tid < SCAN_NBLK) ? bsum[tid] : 0;
    __syncthreads();
    for (int off = 1; off < 128; off <<= 1) {
        int t = 0;
        if (tid < 128 && tid >= off) t = s[tid - off];
        __syncthreads();
        if (tid < 128) s[tid] += t;
        __syncthreads();
    }
    const int add = (blockIdx.x == 0) ? 0 : s[blockIdx.x - 1];
    const int base = blockIdx.x * 1024 + tid * 4;
    #pragma unroll
    for (int i = 0; i < 4; i++) {
        int idx = base + i;
        if (idx < NBINS) offs[idx] += add;
    }
}

// ---- build: permute edges into dst-sorted order (offs -> inclusive ends) ---
__global__ __launch_bounds__(256) void build_kernel(
    const int* __restrict__ ei, const float* __restrict__ ew,
    int* __restrict__ offs, int2* __restrict__ sw)
{
    int e = blockIdx.x * 256 + threadIdx.x;
    if (e >= EE) return;
    int dst = ei[EE + e];
    int p = atomicAdd(&offs[dst], 1);
    sw[p] = make_int2(ei[e], __float_as_int(ew[e]));
}

// ---- aggregate (top tier): fp16 gather, half-wave per node -----------------
__global__ __launch_bounds__(256) void aggregate_h_kernel(
    const short* __restrict__ xh, const int* __restrict__ offs,
    const int2* __restrict__ sw, float* __restrict__ out)
{
    const int node = blockIdx.x * 8 + (threadIdx.x >> 5);
    const int fl   = threadIdx.x & 31;
    if (node >= NN) return;
    const int beg = (node == 0) ? 0 : offs[node - 1];
    const int end = offs[node];
    const half4t* xp = (const half4t*)xh;

    float4 a0 = make_float4(0.f, 0.f, 0.f, 0.f);
    float4 a1 = make_float4(0.f, 0.f, 0.f, 0.f);
    int j = beg;
    for (; j + 1 < end; j += 2) {
        int2 s0 = sw[j];
        int2 s1 = sw[j + 1];
        half4t v0 = xp[(size_t)s0.x * 32 + fl];
        half4t v1 = xp[(size_t)s1.x * 32 + fl];
        float w0 = __int_as_float(s0.y), w1 = __int_as_float(s1.y);
        float2 l0 = __half22float2(v0.a), h0 = __half22float2(v0.b);
        float2 l1 = __half22float2(v1.a), h1 = __half22float2(v1.b);
        a0.x += w0 * l0.x; a0.y += w0 * l0.y; a0.z += w0 * h0.x; a0.w += w0 * h0.y;
        a1.x += w1 * l1.x; a1.y += w1 * l1.y; a1.z += w1 * h1.x; a1.w += w1 * h1.y;
    }
    if (j < end) {
        int2 s0 = sw[j];
        half4t v0 = xp[(size_t)s0.x * 32 + fl];
        float w0 = __int_as_float(s0.y);
        float2 l0 = __half22float2(v0.a), h0 = __half22float2(v0.b);
        a0.x += w0 * l0.x; a0.y += w0 * l0.y; a0.z += w0 * h0.x; a0.w += w0 * h0.y;
    }
    float4 r = make_float4(a0.x + a1.x, a0.y + a1.y, a0.z + a1.z, a0.w + a1.w);
    ((float4*)out)[(size_t)node * 32 + fl] = r;
}

// ---- aggregate (mid tier): fp32 gather -------------------------------------
__global__ __launch_bounds__(256) void aggregate_kernel(
    const float* __restrict__ x, const int* __restrict__ offs,
    const int2* __restrict__ sw, float* __restrict__ out)
{
    const int node = blockIdx.x * 8 + (threadIdx.x >> 5);
    const int fl   = threadIdx.x & 31;
    if (node >= NN) return;
    const int beg = (node == 0) ? 0 : offs[node - 1];
    const int end = offs[node];
    const float4* x4 = (const float4*)x;

    float4 a0 = make_float4(0.f, 0.f, 0.f, 0.f);
    float4 a1 = make_float4(0.f, 0.f, 0.f, 0.f);
    int j = beg;
    for (; j + 1 < end; j += 2) {
        int2 s0 = sw[j];
        int2 s1 = sw[j + 1];
        float4 v0 = x4[(size_t)s0.x * 32 + fl];
        float4 v1 = x4[(size_t)s1.x * 32 + fl];
        float w0 = __int_as_float(s0.y), w1 = __int_as_float(s1.y);
        a0.x += w0 * v0.x; a0.y += w0 * v0.y; a0.z += w0 * v0.z; a0.w += w0 * v0.w;
        a1.x += w1 * v1.x; a1.y += w1 * v1.y; a1.z += w1 * v1.z; a1.w += w1 * v1.w;
    }
    if (j < end) {
        int2 s0 = sw[j];
        float4 v0 = x4[(size_t)s0.x * 32 + fl];
        float w0 = __int_as_float(s0.y);
        a0.x += w0 * v0.x; a0.y += w0 * v0.y; a0.z += w0 * v0.z; a0.w += w0 * v0.w;
    }
    float4 r = make_float4(a0.x + a1.x, a0.y + a1.y, a0.z + a1.z, a0.w + a1.w);
    ((float4*)out)[(size_t)node * 32 + fl] = r;
}

// ---- MFMA GEMM: out = [agg|x] @ [Wrel;Wroot]^T + b  (split-bf16, 3-term) ---
__global__ __launch_bounds__(256) void mfma_gemm_kernel(
    const float* __restrict__ x, const short* __restrict__ Wb,
    const float* __restrict__ bias, float* __restrict__ out)
{
    __shared__ short lds[4 * 128 * 64];   // Ah, Al, Wh, Wl : 64 KB
    short* Ah = lds;
    short* Al = lds + 8192;
    short* Wh = lds + 16384;
    short* Wl = lds + 24576;

    const int tid  = threadIdx.x;
    const int lane = tid & 63;
    const int wave = tid >> 6;
    const int row0 = blockIdx.x * 128;
    const int frow = lane & 15;
    const int fk   = (lane >> 4) * 8;

    floatx4 acc[2][8];
    #pragma unroll
    for (int nf = 0; nf < 8; nf++) {
        float b = bias[nf * 16 + frow];
        #pragma unroll
        for (int mf = 0; mf < 2; mf++) acc[mf][nf] = (floatx4){b, b, b, b};
    }

    for (int kc = 0; kc < 4; kc++) {
        const float* A = (kc < 2) ? out : x;     // K<128 -> agg (in out)
        const int kcol = (kc & 1) * 64;
        __syncthreads();
        #pragma unroll
        for (int i = 0; i < 8; i++) {
            int e = (i * 256 + tid) * 4;
            int r = e >> 6, k = e & 63;
            int rg = row0 + r;
            float4 v = (rg < NN) ? *(const float4*)&A[(size_t)rg * D + kcol + k]
                                 : make_float4(0.f, 0.f, 0.f, 0.f);
            short4 h, l;
            split_bf16(v.x, h.x, l.x);
            split_bf16(v.y, h.y, l.y);
            split_bf16(v.z, h.z, l.z);
            split_bf16(v.w, h.w, l.w);
            int sidx = r * 64 + (((k >> 3) ^ (r & 7)) << 3) + (k & 7);
            *(short4*)&Ah[sidx] = h;
            *(short4*)&Al[sidx] = l;
        }
        #pragma unroll
        for (int i = 0; i < 4; i++) {
            int e = (i * 256 + tid) * 8;
            int c = e >> 6, k = e & 63;
            int sidx = c * 64 + (((k >> 3) ^ (c & 7)) << 3);
            int g = c * 256 + kc * 64 + k;
            *(short8v*)&Wh[sidx] = *(const short8v*)&Wb[g];
            *(short8v*)&Wl[sidx] = *(const short8v*)&Wb[32768 + g];
        }
        __syncthreads();

        const int arow = wave * 32;
        #pragma unroll
        for (int kf = 0; kf < 2; kf++) {
            const int kblk = (kf * 32 + fk) >> 3;
            short8v ah[2], al[2];
            #pragma unroll
            for (int mf = 0; mf < 2; mf++) {
                int r = arow + mf * 16 + frow;
                int idx = r * 64 + ((kblk ^ (r & 7)) << 3);
                ah[mf] = *(const short8v*)&Ah[idx];
                al[mf] = *(const short8v*)&Al[idx];
            }
            #pragma unroll
            for (int nf = 0; nf < 8; nf++) {
                int cc = nf * 16 + frow;
                int idx = cc * 64 + ((kblk ^ (cc & 7)) << 3);
                short8v bh = *(const short8v*)&Wh[idx];
                short8v bl = *(const short8v*)&Wl[idx];
                #pragma unroll
                for (int mf = 0; mf < 2; mf++) {
                    acc[mf][nf] = __builtin_amdgcn_mfma_f32_16x16x32_bf16(ah[mf], bh, acc[mf][nf], 0, 0, 0);
                    acc[mf][nf] = __builtin_amdgcn_mfma_f32_16x16x32_bf16(al[mf], bh, acc[mf][nf], 0, 0, 0);
                    acc[mf][nf] = __builtin_amdgcn_mfma_f32_16x16x32_bf16(ah[mf], bl, acc[mf][nf], 0, 0, 0);
                }
            }
        }
    }

    const int orow = row0 + wave * 32;
    #pragma unroll
    for (int mf = 0; mf < 2; mf++) {
        #pragma unroll
        for (int j = 0; j < 4; j++) {
            int r = orow + mf * 16 + (lane >> 4) * 4 + j;
            if (r < NN) {
                #pragma unroll
                for (int nf = 0; nf < 8; nf++)
                    out[(size_t)r * D + nf * 16 + (lane & 15)] = acc[mf][nf][j];
            }
        }
    }
}

// ---- fallback fp32 GEMM (atomic tier only) ---------------------------------
__global__ __launch_bounds__(512) void gemm_kernel(
    const float* __restrict__ x, const float* __restrict__ Wrel,
    const float* __restrict__ Wroot, const float* __restrict__ bias,
    float* out)
{
    __shared__ float AtT[128][65];
    const int tid  = threadIdx.x;
    const int lane = tid & 63;
    const int wid  = __builtin_amdgcn_readfirstlane(tid >> 6);
    const int row0 = blockIdx.x * 64;
    float acc[16];
    {
        const float* bb = bias + wid * 16;
        #pragma unroll
        for (int c = 0; c < 16; c++) acc[c] = bb[c];
    }
    for (int phase = 0; phase < 2; phase++) {
        const float* A = phase ? x : out;
        const float* W = (phase ? Wroot : Wrel) + wid * 16 * D;
        __syncthreads();
        #pragma unroll
        for (int i = 0; i < 16; i++) {
            int e = i * 512 + tid;
            int r = e >> 7, k = e & 127;
            int rg = row0 + r;
            AtT[k][r] = (rg < NN) ? A[rg * D + k] : 0.0f;
        }
        __syncthreads();
        for (int k4 = 0; k4 < 32; k4++) {
            float a0 = AtT[k4 * 4 + 0][lane];
            float a1 = AtT[k4 * 4 + 1][lane];
            float a2 = AtT[k4 * 4 + 2][lane];
            float a3 = AtT[k4 * 4 + 3][lane];
            #pragma unroll
            for (int c = 0; c < 16; c++) {
                const float* wp = W + c * D + k4 * 4;
                acc[c] += a0 * wp[0] + a1 * wp[1] + a2 * wp[2] + a3 * wp[3];
            }
        }
    }
    __syncthreads();
    #pragma unroll
    for (int c = 0; c < 16; c++)
        AtT[wid * 16 + c][lane] = acc[c];
    __syncthreads();
    #pragma unroll
    for (int i = 0; i < 16; i++) {
        int e = i * 512 + tid;
        int r = e >> 7, col = e & 127;
        int rg = row0 + r;
        if (rg < NN) out[rg * D + col] = AtT[col][r];
    }
}

extern "C" void kernel_launch(void* const* d_in, const int* in_sizes, int n_in,
                              void* d_out, int out_size, void* d_ws, size_t ws_size,
                              hipStream_t stream) {
    const float* x     = (const float*)d_in[0];
    const int*   ei    = (const int*)  d_in[1];
    const float* ew    = (const float*)d_in[2];
    const float* Wrel  = (const float*)d_in[3];
    const float* Wroot = (const float*)d_in[4];
    const float* bias  = (const float*)d_in[5];
    float*       out   = (float*)d_out;

    const int eb = (EE + 255) / 256;

    if (ws_size >= (size_t)WS_INTS_TOP * sizeof(int)) {
        int* w = (int*)d_ws;
        int*   cnt  = w + WS_CNT;
        int*   offs = w + WS_OFFS;
        int*   bsum = w + WS_BSUM;
        int2*  sw   = (int2*)(w + WS_SW);
        short* Wb   = (short*)(w + WS_WCONV);
        short* xh   = (short*)(w + WS_XH);

        hipMemsetAsync(cnt, 0, NBINS * sizeof(int), stream);
        prep_kernel<<<PREP_XB + PREP_WB + PREP_HB, 256, 0, stream>>>(
            x, Wrel, Wroot, ei, xh, Wb, cnt);
        scanA_kernel<<<SCAN_NBLK, 256, 0, stream>>>(cnt, offs, bsum);
        scanC_kernel<<<SCAN_NBLK, 256, 0, stream>>>(offs, bsum);
        build_kernel<<<eb, 256, 0, stream>>>(ei, ew, offs, sw);
        aggregate_h_kernel<<<NN / 8, 256, 0, stream>>>(xh, offs, sw, out);
        mfma_gemm_kernel<<<(NN + 127) / 128, 256, 0, stream>>>(x, Wb, bias, out);
    } else if (ws_size >= (size_t)WS_INTS_MID * sizeof(int)) {
        int* w = (int*)d_ws;
        int*   cnt  = w + WS_CNT;
        int*   offs = w + WS_OFFS;
        int*   bsum = w + WS_BSUM;
        int2*  sw   = (int2*)(w + WS_SW);
        short* Wb   = (short*)(w + WS_WCONV);

        hipMemsetAsync(cnt, 0, NBINS * sizeof(int), stream);
        wconv_kernel<<<128, 256, 0, stream>>>(Wrel, Wroot, Wb);
        hist_kernel <<<eb, 256, 0, stream>>>(ei, cnt);
        scanA_kernel<<<SCAN_NBLK, 256, 0, stream>>>(cnt, offs, bsum);
        scanC_kernel<<<SCAN_NBLK, 256, 0, stream>>>(offs, bsum);
        build_kernel<<<eb, 256, 0, stream>>>(ei, ew, offs, sw);
        aggregate_kernel<<<NN / 8, 256, 0, stream>>>(x, offs, sw, out);
        mfma_gemm_kernel<<<(NN + 127) / 128, 256, 0, stream>>>(x, Wb, bias, out);
    } else {
        hipMemsetAsync(out, 0, (size_t)NN * D * sizeof(float), stream);
        scatter_kernel<<<(EE * 128) / 256, 256, 0, stream>>>(x, ei, ew, out);
        gemm_kernel<<<(NN + 63) / 64, 512, 0, stream>>>(x, Wrel, Wroot, bias, out);
    }
}

// Round 6
// 143.577 us; speedup vs baseline: 3.2127x; 1.1221x over previous
//
#include <hip/hip_runtime.h>
#include <hip/hip_fp16.h>

#define NN 100000
#define EE 640000
#define D 128
#define NBINS NN
#define SCAN_NBLK 98          // ceil(100000/1024)

// ---------------------------------------------------------------------------
// TOP-tier workspace layout (4-byte units):
//   cnt  [0      , 100000)    histogram (zeroed each call)
//   offs [100000 , 200000)    exclusive scan; build mutates to inclusive-end
//   bsum [200000 , 200128)    per-scan-block sums
//   sw   [200192 , 1480192)   packed (src, w) int2, dst-sorted
//   Wf   [1480192, 1496576)   W as f16 [128 c][256 k]
//   xh   [1496576, 7896576)   x as f16 [100000][128]
// agg (f16) lives in the upper 256B of each 512B out row.
// ---------------------------------------------------------------------------
#define WS_CNT      0
#define WS_OFFS     100000
#define WS_BSUM     200000
#define WS_SW       200192
#define WS_WF       1480192
#define WS_XH       1496576
#define WS_INTS_TOP 7896576

// MID-tier (R4 fp32 path) layout
#define WS_WCONV    1480192
#define WS_INTS_MID 1512960

// prep_kernel block partition
#define PREP_XB 6250          // x->fp16 : 6250*256*8  = 12.8M elems
#define PREP_WB 128           // W->f16  : 128*256     = 32768 elems
#define PREP_HB 2500          // hist    : 2500*256    = 640K edges

typedef __attribute__((ext_vector_type(8))) short    short8v;
typedef __attribute__((ext_vector_type(8))) _Float16 half8v;
typedef __attribute__((ext_vector_type(4))) float    floatx4;
struct __align__(8) half4t { __half2 a, b; };

__device__ inline void split_bf16(float f, short& h, short& l) {
    unsigned u  = __float_as_uint(f);
    unsigned hb = u & 0xFFFF0000u;
    h = (short)(u >> 16);
    float fl = f - __uint_as_float(hb);
    l = (short)(__float_as_uint(fl) >> 16);
}

// ---- fallback path (atomic scatter), used only if ws tiny ------------------
__global__ __launch_bounds__(256) void scatter_kernel(
    const float* __restrict__ x, const int* __restrict__ ei,
    const float* __restrict__ ew, float* agg)
{
    int gid = blockIdx.x * 256 + threadIdx.x;
    int e = gid >> 7, f = gid & 127;
    if (e >= EE) return;
    float v = x[ei[e] * D + f] * ew[e];
    unsafeAtomicAdd(&agg[ei[EE + e] * D + f], v);
}

// ---- fused prep: x->fp16 | W->f16 | dst histogram --------------------------
__global__ __launch_bounds__(256) void prep_kernel(
    const float* __restrict__ x, const float* __restrict__ Wrel,
    const float* __restrict__ Wroot, const int* __restrict__ ei,
    short* __restrict__ xh, short* __restrict__ Wf, int* __restrict__ cnt)
{
    const int b = blockIdx.x;
    if (b < PREP_XB) {
        int i = (b * 256 + threadIdx.x) * 8;
        float4 v0 = *(const float4*)&x[i];
        float4 v1 = *(const float4*)&x[i + 4];
        short8v hv;
        hv[0] = (short)__half_as_ushort(__float2half(v0.x));
        hv[1] = (short)__half_as_ushort(__float2half(v0.y));
        hv[2] = (short)__half_as_ushort(__float2half(v0.z));
        hv[3] = (short)__half_as_ushort(__float2half(v0.w));
        hv[4] = (short)__half_as_ushort(__float2half(v1.x));
        hv[5] = (short)__half_as_ushort(__float2half(v1.y));
        hv[6] = (short)__half_as_ushort(__float2half(v1.z));
        hv[7] = (short)__half_as_ushort(__float2half(v1.w));
        *(short8v*)&xh[i] = hv;
    } else if (b < PREP_XB + PREP_WB) {
        int i = (b - PREP_XB) * 256 + threadIdx.x;   // 0..32767
        int c = i >> 8, k = i & 255;
        float f = (k < 128) ? Wrel[c * 128 + k] : Wroot[c * 128 + (k - 128)];
        Wf[i] = (short)__half_as_ushort(__float2half(f));
    } else {
        int e = (b - PREP_XB - PREP_WB) * 256 + threadIdx.x;
        if (e < EE) atomicAdd(&cnt[ei[EE + e]], 1);
    }
}

// ---- standalone hist / wconv (mid tier) ------------------------------------
__global__ __launch_bounds__(256) void hist_kernel(
    const int* __restrict__ ei, int* __restrict__ cnt)
{
    int e = blockIdx.x * 256 + threadIdx.x;
    if (e < EE) atomicAdd(&cnt[ei[EE + e]], 1);
}

__global__ __launch_bounds__(256) void wconv_kernel(
    const float* __restrict__ Wrel, const float* __restrict__ Wroot,
    short* __restrict__ Wb)
{
    int i = blockIdx.x * 256 + threadIdx.x;
    int c = i >> 8, k = i & 255;
    float f = (k < 128) ? Wrel[c * 128 + k] : Wroot[c * 128 + (k - 128)];
    short h, l;
    split_bf16(f, h, l);
    Wb[i] = h;
    Wb[32768 + i] = l;
}

// ---- scanA: block-level exclusive scan (1024 elems/block) ------------------
__global__ __launch_bounds__(256) void scanA_kernel(
    const int* __restrict__ cnt, int* __restrict__ offs, int* __restrict__ bsum)
{
    __shared__ int tsum[256];
    const int tid = threadIdx.x;
    const int base = blockIdx.x * 1024 + tid * 4;
    int v[4], s = 0;
    #pragma unroll
    for (int i = 0; i < 4; i++) {
        int idx = base + i;
        v[i] = (idx < NBINS) ? cnt[idx] : 0;
        s += v[i];
    }
    tsum[tid] = s;
    __syncthreads();
    for (int off = 1; off < 256; off <<= 1) {
        int t = (tid >= off) ? tsum[tid - off] : 0;
        __syncthreads();
        tsum[tid] += t;
        __syncthreads();
    }
    int run = tsum[tid] - s;
    #pragma unroll
    for (int i = 0; i < 4; i++) {
        int idx = base + i;
        if (idx < NBINS) offs[idx] = run;
        run += v[i];
    }
    if (tid == 255) bsum[blockIdx.x] = tsum[255];
}

// ---- scanC: every block scans bsum in LDS, adds its prefix -----------------
__global__ __launch_bounds__(256) void scanC_kernel(
    int* __restrict__ offs, const int* __restrict__ bsum)
{
    __shared__ int s[128];
    const int tid = threadIdx.x;
    if (tid < 128) s[tid] = (tid < SCAN_NBLK) ? bsum[tid] : 0;
    __syncthreads();
    for (int off = 1; off < 128; off <<= 1) {
        int t = 0;
        if (tid < 128 && tid >= off) t = s[tid - off];
        __syncthreads();
        if (tid < 128) s[tid] += t;
        __syncthreads();
    }
    const int add = (blockIdx.x == 0) ? 0 : s[blockIdx.x - 1];
    const int base = blockIdx.x * 1024 + tid * 4;
    #pragma unroll
    for (int i = 0; i < 4; i++) {
        int idx = base + i;
        if (idx < NBINS) offs[idx] += add;
    }
}

// ---- build: permute edges into dst-sorted order (offs -> inclusive ends) ---
__global__ __launch_bounds__(256) void build_kernel(
    const int* __restrict__ ei, const float* __restrict__ ew,
    int* __restrict__ offs, int2* __restrict__ sw)
{
    int e = blockIdx.x * 256 + threadIdx.x;
    if (e >= EE) return;
    int dst = ei[EE + e];
    int p = atomicAdd(&offs[dst], 1);
    sw[p] = make_int2(ei[e], __float_as_int(ew[e]));
}

// ---- aggregate (top): fp16 gather, f16 agg into out-row tail ---------------
__global__ __launch_bounds__(256) void aggregate_h_kernel(
    const short* __restrict__ xh, const int* __restrict__ offs,
    const int2* __restrict__ sw, float* __restrict__ out)
{
    const int node = blockIdx.x * 8 + (threadIdx.x >> 5);
    const int fl   = threadIdx.x & 31;
    if (node >= NN) return;
    const int beg = (node == 0) ? 0 : offs[node - 1];
    const int end = offs[node];
    const half4t* xp = (const half4t*)xh;

    float4 a0 = make_float4(0.f, 0.f, 0.f, 0.f);
    float4 a1 = make_float4(0.f, 0.f, 0.f, 0.f);
    int j = beg;
    for (; j + 1 < end; j += 2) {
        int2 s0 = sw[j];
        int2 s1 = sw[j + 1];
        half4t v0 = xp[(size_t)s0.x * 32 + fl];
        half4t v1 = xp[(size_t)s1.x * 32 + fl];
        float w0 = __int_as_float(s0.y), w1 = __int_as_float(s1.y);
        float2 l0 = __half22float2(v0.a), h0 = __half22float2(v0.b);
        float2 l1 = __half22float2(v1.a), h1 = __half22float2(v1.b);
        a0.x += w0 * l0.x; a0.y += w0 * l0.y; a0.z += w0 * h0.x; a0.w += w0 * h0.y;
        a1.x += w1 * l1.x; a1.y += w1 * l1.y; a1.z += w1 * h1.x; a1.w += w1 * h1.y;
    }
    if (j < end) {
        int2 s0 = sw[j];
        half4t v0 = xp[(size_t)s0.x * 32 + fl];
        float w0 = __int_as_float(s0.y);
        float2 l0 = __half22float2(v0.a), h0 = __half22float2(v0.b);
        a0.x += w0 * l0.x; a0.y += w0 * l0.y; a0.z += w0 * h0.x; a0.w += w0 * h0.y;
    }
    float4 r = make_float4(a0.x + a1.x, a0.y + a1.y, a0.z + a1.z, a0.w + a1.w);
    // agg row tail: bytes [256,512) of out row `node`
    half4t o;
    o.a = __floats2half2_rn(r.x, r.y);
    o.b = __floats2half2_rn(r.z, r.w);
    half4t* op = (half4t*)((char*)out + (size_t)node * 512 + 256);
    op[fl] = o;
}

// ---- aggregate (mid tier): fp32 gather -------------------------------------
__global__ __launch_bounds__(256) void aggregate_kernel(
    const float* __restrict__ x, const int* __restrict__ offs,
    const int2* __restrict__ sw, float* __restrict__ out)
{
    const int node = blockIdx.x * 8 + (threadIdx.x >> 5);
    const int fl   = threadIdx.x & 31;
    if (node >= NN) return;
    const int beg = (node == 0) ? 0 : offs[node - 1];
    const int end = offs[node];
    const float4* x4 = (const float4*)x;

    float4 a0 = make_float4(0.f, 0.f, 0.f, 0.f);
    float4 a1 = make_float4(0.f, 0.f, 0.f, 0.f);
    int j = beg;
    for (; j + 1 < end; j += 2) {
        int2 s0 = sw[j];
        int2 s1 = sw[j + 1];
        float4 v0 = x4[(size_t)s0.x * 32 + fl];
        float4 v1 = x4[(size_t)s1.x * 32 + fl];
        float w0 = __int_as_float(s0.y), w1 = __int_as_float(s1.y);
        a0.x += w0 * v0.x; a0.y += w0 * v0.y; a0.z += w0 * v0.z; a0.w += w0 * v0.w;
        a1.x += w1 * v1.x; a1.y += w1 * v1.y; a1.z += w1 * v1.z; a1.w += w1 * v1.w;
    }
    if (j < end) {
        int2 s0 = sw[j];
        float4 v0 = x4[(size_t)s0.x * 32 + fl];
        float w0 = __int_as_float(s0.y);
        a0.x += w0 * v0.x; a0.y += w0 * v0.y; a0.z += w0 * v0.z; a0.w += w0 * v0.w;
    }
    float4 r = make_float4(a0.x + a1.x, a0.y + a1.y, a0.z + a1.z, a0.w + a1.w);
    ((float4*)out)[(size_t)node * 32 + fl] = r;
}

// ---- f16 MFMA GEMM (top): out = [aggh|xh] @ Wf^T + b -----------------------
// 256 thr = 4 waves, tile 128 rows x 128 cols, K=256 in 4 chunks of 64.
// LDS 32KB (At + Wt, f16, 16B-block XOR swizzle) -> 5 blocks/CU.
// aggh read from own rows' out tail before out rows are overwritten.
__global__ __launch_bounds__(256) void mfma_f16_kernel(
    const short* __restrict__ xh, const short* __restrict__ Wf,
    const float* __restrict__ bias, float* __restrict__ out)
{
    __shared__ short lds[2 * 128 * 64];   // At, Wt : 32 KB
    short* At = lds;
    short* Wt = lds + 8192;

    const int tid  = threadIdx.x;
    const int lane = tid & 63;
    const int wave = tid >> 6;
    const int row0 = blockIdx.x * 128;
    const int frow = lane & 15;

    floatx4 acc[2][8];
    #pragma unroll
    for (int nf = 0; nf < 8; nf++) {
        float b = bias[nf * 16 + frow];
        #pragma unroll
        for (int mf = 0; mf < 2; mf++) acc[mf][nf] = (floatx4){b, b, b, b};
    }

    const short* aggh = (const short*)out;   // f16 view; row n tail = [n*256+128, n*256+256)

    for (int kc = 0; kc < 4; kc++) {
        __syncthreads();
        // stage A tile (pure 16B copies, swizzled)
        #pragma unroll
        for (int i = 0; i < 4; i++) {
            int e = (i * 256 + tid) * 8;
            int r = e >> 6, k = e & 63;
            int rg = row0 + r;
            short8v v = (short8v)0;
            if (rg < NN) {
                if (kc < 2) v = *(const short8v*)&aggh[(size_t)rg * 256 + 128 + kc * 64 + k];
                else        v = *(const short8v*)&xh[(size_t)rg * 128 + (kc - 2) * 64 + k];
            }
            int sidx = r * 64 + (((k >> 3) ^ (r & 7)) << 3);
            *(short8v*)&At[sidx] = v;
        }
        // stage W tile
        #pragma unroll
        for (int i = 0; i < 4; i++) {
            int e = (i * 256 + tid) * 8;
            int c = e >> 6, k = e & 63;
            int sidx = c * 64 + (((k >> 3) ^ (c & 7)) << 3);
            *(short8v*)&Wt[sidx] = *(const short8v*)&Wf[c * 256 + kc * 64 + k];
        }
        __syncthreads();

        const int arow = wave * 32;
        #pragma unroll
        for (int kf = 0; kf < 2; kf++) {
            const int kblk = kf * 4 + (lane >> 4);
            half8v a[2];
            #pragma unroll
            for (int mf = 0; mf < 2; mf++) {
                int r = arow + mf * 16 + frow;
                int idx = r * 64 + ((kblk ^ (r & 7)) << 3);
                a[mf] = *(const half8v*)&At[idx];
            }
            #pragma unroll
            for (int nf = 0; nf < 8; nf++) {
                int cc = nf * 16 + frow;
                int idx = cc * 64 + ((kblk ^ (cc & 7)) << 3);
                half8v b = *(const half8v*)&Wt[idx];
                #pragma unroll
                for (int mf = 0; mf < 2; mf++)
                    acc[mf][nf] = __builtin_amdgcn_mfma_f32_16x16x32_f16(a[mf], b, acc[mf][nf], 0, 0, 0);
            }
        }
    }

    // C/D layout: col = lane&15, row = (lane>>4)*4 + j
    const int orow = row0 + wave * 32;
    #pragma unroll
    for (int mf = 0; mf < 2; mf++) {
        #pragma unroll
        for (int j = 0; j < 4; j++) {
            int r = orow + mf * 16 + (lane >> 4) * 4 + j;
            if (r < NN) {
                #pragma unroll
                for (int nf = 0; nf < 8; nf++)
                    out[(size_t)r * D + nf * 16 + (lane & 15)] = acc[mf][nf][j];
            }
        }
    }
}

// ---- mid-tier MFMA GEMM (split-bf16 3-term, R4 path) -----------------------
__global__ __launch_bounds__(256) void mfma_gemm_kernel(
    const float* __restrict__ x, const short* __restrict__ Wb,
    const float* __restrict__ bias, float* __restrict__ out)
{
    __shared__ short lds[4 * 128 * 64];
    short* Ah = lds;
    short* Al = lds + 8192;
    short* Wh = lds + 16384;
    short* Wl = lds + 24576;

    const int tid  = threadIdx.x;
    const int lane = tid & 63;
    const int wave = tid >> 6;
    const int row0 = blockIdx.x * 128;
    const int frow = lane & 15;
    const int fk   = (lane >> 4) * 8;

    floatx4 acc[2][8];
    #pragma unroll
    for (int nf = 0; nf < 8; nf++) {
        float b = bias[nf * 16 + frow];
        #pragma unroll
        for (int mf = 0; mf < 2; mf++) acc[mf][nf] = (floatx4){b, b, b, b};
    }

    for (int kc = 0; kc < 4; kc++) {
        const float* A = (kc < 2) ? out : x;
        const int kcol = (kc & 1) * 64;
        __syncthreads();
        #pragma unroll
        for (int i = 0; i < 8; i++) {
            int e = (i * 256 + tid) * 4;
            int r = e >> 6, k = e & 63;
            int rg = row0 + r;
            float4 v = (rg < NN) ? *(const float4*)&A[(size_t)rg * D + kcol + k]
                                 : make_float4(0.f, 0.f, 0.f, 0.f);
            short4 h, l;
            split_bf16(v.x, h.x, l.x);
            split_bf16(v.y, h.y, l.y);
            split_bf16(v.z, h.z, l.z);
            split_bf16(v.w, h.w, l.w);
            int sidx = r * 64 + (((k >> 3) ^ (r & 7)) << 3) + (k & 7);
            *(short4*)&Ah[sidx] = h;
            *(short4*)&Al[sidx] = l;
        }
        #pragma unroll
        for (int i = 0; i < 4; i++) {
            int e = (i * 256 + tid) * 8;
            int c = e >> 6, k = e & 63;
            int sidx = c * 64 + (((k >> 3) ^ (c & 7)) << 3);
            int g = c * 256 + kc * 64 + k;
            *(short8v*)&Wh[sidx] = *(const short8v*)&Wb[g];
            *(short8v*)&Wl[sidx] = *(const short8v*)&Wb[32768 + g];
        }
        __syncthreads();

        const int arow = wave * 32;
        #pragma unroll
        for (int kf = 0; kf < 2; kf++) {
            const int kblk = (kf * 32 + fk) >> 3;
            short8v ah[2], al[2];
            #pragma unroll
            for (int mf = 0; mf < 2; mf++) {
                int r = arow + mf * 16 + frow;
                int idx = r * 64 + ((kblk ^ (r & 7)) << 3);
                ah[mf] = *(const short8v*)&Ah[idx];
                al[mf] = *(const short8v*)&Al[idx];
            }
            #pragma unroll
            for (int nf = 0; nf < 8; nf++) {
                int cc = nf * 16 + frow;
                int idx = cc * 64 + ((kblk ^ (cc & 7)) << 3);
                short8v bh = *(const short8v*)&Wh[idx];
                short8v bl = *(const short8v*)&Wl[idx];
                #pragma unroll
                for (int mf = 0; mf < 2; mf++) {
                    acc[mf][nf] = __builtin_amdgcn_mfma_f32_16x16x32_bf16(ah[mf], bh, acc[mf][nf], 0, 0, 0);
                    acc[mf][nf] = __builtin_amdgcn_mfma_f32_16x16x32_bf16(al[mf], bh, acc[mf][nf], 0, 0, 0);
                    acc[mf][nf] = __builtin_amdgcn_mfma_f32_16x16x32_bf16(ah[mf], bl, acc[mf][nf], 0, 0, 0);
                }
            }
        }
    }

    const int orow = row0 + wave * 32;
    #pragma unroll
    for (int mf = 0; mf < 2; mf++) {
        #pragma unroll
        for (int j = 0; j < 4; j++) {
            int r = orow + mf * 16 + (lane >> 4) * 4 + j;
            if (r < NN) {
                #pragma unroll
                for (int nf = 0; nf < 8; nf++)
                    out[(size_t)r * D + nf * 16 + (lane & 15)] = acc[mf][nf][j];
            }
        }
    }
}

// ---- fallback fp32 GEMM (atomic tier only) ---------------------------------
__global__ __launch_bounds__(512) void gemm_kernel(
    const float* __restrict__ x, const float* __restrict__ Wrel,
    const float* __restrict__ Wroot, const float* __restrict__ bias,
    float* out)
{
    __shared__ float AtT[128][65];
    const int tid  = threadIdx.x;
    const int lane = tid & 63;
    const int wid  = __builtin_amdgcn_readfirstlane(tid >> 6);
    const int row0 = blockIdx.x * 64;
    float acc[16];
    {
        const float* bb = bias + wid * 16;
        #pragma unroll
        for (int c = 0; c < 16; c++) acc[c] = bb[c];
    }
    for (int phase = 0; phase < 2; phase++) {
        const float* A = phase ? x : out;
        const float* W = (phase ? Wroot : Wrel) + wid * 16 * D;
        __syncthreads();
        #pragma unroll
        for (int i = 0; i < 16; i++) {
            int e = i * 512 + tid;
            int r = e >> 7, k = e & 127;
            int rg = row0 + r;
            AtT[k][r] = (rg < NN) ? A[rg * D + k] : 0.0f;
        }
        __syncthreads();
        for (int k4 = 0; k4 < 32; k4++) {
            float a0 = AtT[k4 * 4 + 0][lane];
            float a1 = AtT[k4 * 4 + 1][lane];
            float a2 = AtT[k4 * 4 + 2][lane];
            float a3 = AtT[k4 * 4 + 3][lane];
            #pragma unroll
            for (int c = 0; c < 16; c++) {
                const float* wp = W + c * D + k4 * 4;
                acc[c] += a0 * wp[0] + a1 * wp[1] + a2 * wp[2] + a3 * wp[3];
            }
        }
    }
    __syncthreads();
    #pragma unroll
    for (int c = 0; c < 16; c++)
        AtT[wid * 16 + c][lane] = acc[c];
    __syncthreads();
    #pragma unroll
    for (int i = 0; i < 16; i++) {
        int e = i * 512 + tid;
        int r = e >> 7, col = e & 127;
        int rg = row0 + r;
        if (rg < NN) out[rg * D + col] = AtT[col][r];
    }
}

extern "C" void kernel_launch(void* const* d_in, const int* in_sizes, int n_in,
                              void* d_out, int out_size, void* d_ws, size_t ws_size,
                              hipStream_t stream) {
    const float* x     = (const float*)d_in[0];
    const int*   ei    = (const int*)  d_in[1];
    const float* ew    = (const float*)d_in[2];
    const float* Wrel  = (const float*)d_in[3];
    const float* Wroot = (const float*)d_in[4];
    const float* bias  = (const float*)d_in[5];
    float*       out   = (float*)d_out;

    const int eb = (EE + 255) / 256;

    if (ws_size >= (size_t)WS_INTS_TOP * sizeof(int)) {
        int* w = (int*)d_ws;
        int*   cnt  = w + WS_CNT;
        int*   offs = w + WS_OFFS;
        int*   bsum = w + WS_BSUM;
        int2*  sw   = (int2*)(w + WS_SW);
        short* Wf   = (short*)(w + WS_WF);
        short* xh   = (short*)(w + WS_XH);

        hipMemsetAsync(cnt, 0, NBINS * sizeof(int), stream);
        prep_kernel<<<PREP_XB + PREP_WB + PREP_HB, 256, 0, stream>>>(
            x, Wrel, Wroot, ei, xh, Wf, cnt);
        scanA_kernel<<<SCAN_NBLK, 256, 0, stream>>>(cnt, offs, bsum);
        scanC_kernel<<<SCAN_NBLK, 256, 0, stream>>>(offs, bsum);
        build_kernel<<<eb, 256, 0, stream>>>(ei, ew, offs, sw);
        aggregate_h_kernel<<<NN / 8, 256, 0, stream>>>(xh, offs, sw, out);
        mfma_f16_kernel<<<(NN + 127) / 128, 256, 0, stream>>>(xh, Wf, bias, out);
    } else if (ws_size >= (size_t)WS_INTS_MID * sizeof(int)) {
        int* w = (int*)d_ws;
        int*   cnt  = w + WS_CNT;
        int*   offs = w + WS_OFFS;
        int*   bsum = w + WS_BSUM;
        int2*  sw   = (int2*)(w + WS_SW);
        short* Wb   = (short*)(w + WS_WCONV);

        hipMemsetAsync(cnt, 0, NBINS * sizeof(int), stream);
        wconv_kernel<<<128, 256, 0, stream>>>(Wrel, Wroot, Wb);
        hist_kernel <<<eb, 256, 0, stream>>>(ei, cnt);
        scanA_kernel<<<SCAN_NBLK, 256, 0, stream>>>(cnt, offs, bsum);
        scanC_kernel<<<SCAN_NBLK, 256, 0, stream>>>(offs, bsum);
        build_kernel<<<eb, 256, 0, stream>>>(ei, ew, offs, sw);
        aggregate_kernel<<<NN / 8, 256, 0, stream>>>(x, offs, sw, out);
        mfma_gemm_kernel<<<(NN + 127) / 128, 256, 0, stream>>>(x, Wb, bias, out);
    } else {
        hipMemsetAsync(out, 0, (size_t)NN * D * sizeof(float), stream);
        scatter_kernel<<<(EE * 128) / 256, 256, 0, stream>>>(x, ei, ew, out);
        gemm_kernel<<<(NN + 63) / 64, 512, 0, stream>>>(x, Wrel, Wroot, bias, out);
    }
}

// Round 7
// 138.942 us; speedup vs baseline: 3.3199x; 1.0334x over previous
//
#include <hip/hip_runtime.h>
#include <hip/hip_fp16.h>

#define NN 100000
#define EE 640000
#define D 128
#define NBINS NN
#define SCAN_NBLK 98          // ceil(100000/1024)

// ---------------------------------------------------------------------------
// TOP-tier workspace layout (4-byte units):
//   cnt  [0      , 100000)    histogram (zeroed each call by zero_cnt_kernel)
//   offs [100000 , 200000)    exclusive scan; build mutates to inclusive-end
//   bsum [200000 , 200128)    per-scan-block sums
//   sw   [200192 , 1480192)   packed (src, w) int2, dst-sorted
//   Wf   [1480192, 1496576)   W as f16 [128 c][256 k]
//   xh   [1496576, 7896576)   x as f16 [100000][128]
// agg (f16) lives in the upper 256B of each 512B out row.
// ---------------------------------------------------------------------------
#define WS_CNT      0
#define WS_OFFS     100000
#define WS_BSUM     200000
#define WS_SW       200192
#define WS_WF       1480192
#define WS_XH       1496576
#define WS_INTS_TOP 7896576

// MID-tier (R4 fp32 path) layout
#define WS_WCONV    1480192
#define WS_INTS_MID 1512960

// prep_kernel block partition
#define PREP_XB 3125          // x->fp16 : 3125*256*16 = 12.8M elems
#define PREP_WB 128           // W->f16  : 128*256     = 32768 elems
#define PREP_HB 2500          // hist    : 2500*256    = 640K edges

typedef __attribute__((ext_vector_type(8))) short    short8v;
typedef __attribute__((ext_vector_type(8))) _Float16 half8v;
typedef __attribute__((ext_vector_type(4))) float    floatx4;
struct __align__(8) half4t { __half2 a, b; };

__device__ inline void split_bf16(float f, short& h, short& l) {
    unsigned u  = __float_as_uint(f);
    unsigned hb = u & 0xFFFF0000u;
    h = (short)(u >> 16);
    float fl = f - __uint_as_float(hb);
    l = (short)(__float_as_uint(fl) >> 16);
}

// ---- fallback path (atomic scatter), used only if ws tiny ------------------
__global__ __launch_bounds__(256) void scatter_kernel(
    const float* __restrict__ x, const int* __restrict__ ei,
    const float* __restrict__ ew, float* agg)
{
    int gid = blockIdx.x * 256 + threadIdx.x;
    int e = gid >> 7, f = gid & 127;
    if (e >= EE) return;
    float v = x[ei[e] * D + f] * ew[e];
    unsafeAtomicAdd(&agg[ei[EE + e] * D + f], v);
}

// ---- 0. zero the histogram (replaces rocclr fillBuffer) --------------------
__global__ __launch_bounds__(256) void zero_cnt_kernel(int* __restrict__ cnt)
{
    int i = blockIdx.x * 256 + threadIdx.x;
    if (i < NBINS) cnt[i] = 0;
}

// ---- fused prep: x->fp16 | W->f16 | dst histogram --------------------------
__global__ __launch_bounds__(256) void prep_kernel(
    const float* __restrict__ x, const float* __restrict__ Wrel,
    const float* __restrict__ Wroot, const int* __restrict__ ei,
    short* __restrict__ xh, short* __restrict__ Wf, int* __restrict__ cnt)
{
    const int b = blockIdx.x;
    if (b < PREP_XB) {
        // 4 independent 16B-load -> 8B-store chains per thread (coalesced)
        const int base = b * 4096 + threadIdx.x * 4;   // f32 index
        float4 v[4];
        #pragma unroll
        for (int u = 0; u < 4; u++)
            v[u] = *(const float4*)&x[base + u * 1024];
        #pragma unroll
        for (int u = 0; u < 4; u++) {
            short4 h;
            h.x = (short)__half_as_ushort(__float2half(v[u].x));
            h.y = (short)__half_as_ushort(__float2half(v[u].y));
            h.z = (short)__half_as_ushort(__float2half(v[u].z));
            h.w = (short)__half_as_ushort(__float2half(v[u].w));
            *(short4*)&xh[base + u * 1024] = h;
        }
    } else if (b < PREP_XB + PREP_WB) {
        int i = (b - PREP_XB) * 256 + threadIdx.x;   // 0..32767
        int c = i >> 8, k = i & 255;
        float f = (k < 128) ? Wrel[c * 128 + k] : Wroot[c * 128 + (k - 128)];
        Wf[i] = (short)__half_as_ushort(__float2half(f));
    } else {
        int e = (b - PREP_XB - PREP_WB) * 256 + threadIdx.x;
        if (e < EE) atomicAdd(&cnt[ei[EE + e]], 1);
    }
}

// ---- standalone hist / wconv (mid tier) ------------------------------------
__global__ __launch_bounds__(256) void hist_kernel(
    const int* __restrict__ ei, int* __restrict__ cnt)
{
    int e = blockIdx.x * 256 + threadIdx.x;
    if (e < EE) atomicAdd(&cnt[ei[EE + e]], 1);
}

__global__ __launch_bounds__(256) void wconv_kernel(
    const float* __restrict__ Wrel, const float* __restrict__ Wroot,
    short* __restrict__ Wb)
{
    int i = blockIdx.x * 256 + threadIdx.x;
    int c = i >> 8, k = i & 255;
    float f = (k < 128) ? Wrel[c * 128 + k] : Wroot[c * 128 + (k - 128)];
    short h, l;
    split_bf16(f, h, l);
    Wb[i] = h;
    Wb[32768 + i] = l;
}

// ---- scanA: block-level exclusive scan (1024 elems/block) ------------------
__global__ __launch_bounds__(256) void scanA_kernel(
    const int* __restrict__ cnt, int* __restrict__ offs, int* __restrict__ bsum)
{
    __shared__ int tsum[256];
    const int tid = threadIdx.x;
    const int base = blockIdx.x * 1024 + tid * 4;
    int v[4], s = 0;
    #pragma unroll
    for (int i = 0; i < 4; i++) {
        int idx = base + i;
        v[i] = (idx < NBINS) ? cnt[idx] : 0;
        s += v[i];
    }
    tsum[tid] = s;
    __syncthreads();
    for (int off = 1; off < 256; off <<= 1) {
        int t = (tid >= off) ? tsum[tid - off] : 0;
        __syncthreads();
        tsum[tid] += t;
        __syncthreads();
    }
    int run = tsum[tid] - s;
    #pragma unroll
    for (int i = 0; i < 4; i++) {
        int idx = base + i;
        if (idx < NBINS) offs[idx] = run;
        run += v[i];
    }
    if (tid == 255) bsum[blockIdx.x] = tsum[255];
}

// ---- scanC: every block scans bsum in LDS, adds its prefix -----------------
__global__ __launch_bounds__(256) void scanC_kernel(
    int* __restrict__ offs, const int* __restrict__ bsum)
{
    __shared__ int s[128];
    const int tid = threadIdx.x;
    if (tid < 128) s[tid] = (tid < SCAN_NBLK) ? bsum[tid] : 0;
    __syncthreads();
    for (int off = 1; off < 128; off <<= 1) {
        int t = 0;
        if (tid < 128 && tid >= off) t = s[tid - off];
        __syncthreads();
        if (tid < 128) s[tid] += t;
        __syncthreads();
    }
    const int add = (blockIdx.x == 0) ? 0 : s[blockIdx.x - 1];
    const int base = blockIdx.x * 1024 + tid * 4;
    #pragma unroll
    for (int i = 0; i < 4; i++) {
        int idx = base + i;
        if (idx < NBINS) offs[idx] += add;
    }
}

// ---- build: permute edges into dst-sorted order (offs -> inclusive ends) ---
__global__ __launch_bounds__(256) void build_kernel(
    const int* __restrict__ ei, const float* __restrict__ ew,
    int* __restrict__ offs, int2* __restrict__ sw)
{
    int e = blockIdx.x * 256 + threadIdx.x;
    if (e >= EE) return;
    int dst = ei[EE + e];
    int p = atomicAdd(&offs[dst], 1);
    sw[p] = make_int2(ei[e], __float_as_int(ew[e]));
}

// ---- aggregate (top): fp16 gather 4-deep, f16 agg into out-row tail --------
__global__ __launch_bounds__(256) void aggregate_h_kernel(
    const short* __restrict__ xh, const int* __restrict__ offs,
    const int2* __restrict__ sw, float* __restrict__ out)
{
    const int node = blockIdx.x * 8 + (threadIdx.x >> 5);
    const int fl   = threadIdx.x & 31;
    if (node >= NN) return;
    const int beg = (node == 0) ? 0 : offs[node - 1];
    const int end = offs[node];
    const half4t* xp = (const half4t*)xh;

    float4 a0 = make_float4(0.f, 0.f, 0.f, 0.f);
    float4 a1 = make_float4(0.f, 0.f, 0.f, 0.f);
    int j = beg;
    for (; j + 3 < end; j += 4) {
        int2 s0 = sw[j], s1 = sw[j + 1], s2 = sw[j + 2], s3 = sw[j + 3];
        half4t v0 = xp[(size_t)s0.x * 32 + fl];
        half4t v1 = xp[(size_t)s1.x * 32 + fl];
        half4t v2 = xp[(size_t)s2.x * 32 + fl];
        half4t v3 = xp[(size_t)s3.x * 32 + fl];
        float w0 = __int_as_float(s0.y), w1 = __int_as_float(s1.y);
        float w2 = __int_as_float(s2.y), w3 = __int_as_float(s3.y);
        float2 l0 = __half22float2(v0.a), h0 = __half22float2(v0.b);
        float2 l1 = __half22float2(v1.a), h1 = __half22float2(v1.b);
        float2 l2 = __half22float2(v2.a), h2 = __half22float2(v2.b);
        float2 l3 = __half22float2(v3.a), h3 = __half22float2(v3.b);
        a0.x += w0 * l0.x; a0.y += w0 * l0.y; a0.z += w0 * h0.x; a0.w += w0 * h0.y;
        a1.x += w1 * l1.x; a1.y += w1 * l1.y; a1.z += w1 * h1.x; a1.w += w1 * h1.y;
        a0.x += w2 * l2.x; a0.y += w2 * l2.y; a0.z += w2 * h2.x; a0.w += w2 * h2.y;
        a1.x += w3 * l3.x; a1.y += w3 * l3.y; a1.z += w3 * h3.x; a1.w += w3 * h3.y;
    }
    for (; j + 1 < end; j += 2) {
        int2 s0 = sw[j], s1 = sw[j + 1];
        half4t v0 = xp[(size_t)s0.x * 32 + fl];
        half4t v1 = xp[(size_t)s1.x * 32 + fl];
        float w0 = __int_as_float(s0.y), w1 = __int_as_float(s1.y);
        float2 l0 = __half22float2(v0.a), h0 = __half22float2(v0.b);
        float2 l1 = __half22float2(v1.a), h1 = __half22float2(v1.b);
        a0.x += w0 * l0.x; a0.y += w0 * l0.y; a0.z += w0 * h0.x; a0.w += w0 * h0.y;
        a1.x += w1 * l1.x; a1.y += w1 * l1.y; a1.z += w1 * h1.x; a1.w += w1 * h1.y;
    }
    if (j < end) {
        int2 s0 = sw[j];
        half4t v0 = xp[(size_t)s0.x * 32 + fl];
        float w0 = __int_as_float(s0.y);
        float2 l0 = __half22float2(v0.a), h0 = __half22float2(v0.b);
        a0.x += w0 * l0.x; a0.y += w0 * l0.y; a0.z += w0 * h0.x; a0.w += w0 * h0.y;
    }
    float4 r = make_float4(a0.x + a1.x, a0.y + a1.y, a0.z + a1.z, a0.w + a1.w);
    // agg row tail: bytes [256,512) of out row `node`
    half4t o;
    o.a = __floats2half2_rn(r.x, r.y);
    o.b = __floats2half2_rn(r.z, r.w);
    half4t* op = (half4t*)((char*)out + (size_t)node * 512 + 256);
    op[fl] = o;
}

// ---- aggregate (mid tier): fp32 gather -------------------------------------
__global__ __launch_bounds__(256) void aggregate_kernel(
    const float* __restrict__ x, const int* __restrict__ offs,
    const int2* __restrict__ sw, float* __restrict__ out)
{
    const int node = blockIdx.x * 8 + (threadIdx.x >> 5);
    const int fl   = threadIdx.x & 31;
    if (node >= NN) return;
    const int beg = (node == 0) ? 0 : offs[node - 1];
    const int end = offs[node];
    const float4* x4 = (const float4*)x;

    float4 a0 = make_float4(0.f, 0.f, 0.f, 0.f);
    float4 a1 = make_float4(0.f, 0.f, 0.f, 0.f);
    int j = beg;
    for (; j + 1 < end; j += 2) {
        int2 s0 = sw[j];
        int2 s1 = sw[j + 1];
        float4 v0 = x4[(size_t)s0.x * 32 + fl];
        float4 v1 = x4[(size_t)s1.x * 32 + fl];
        float w0 = __int_as_float(s0.y), w1 = __int_as_float(s1.y);
        a0.x += w0 * v0.x; a0.y += w0 * v0.y; a0.z += w0 * v0.z; a0.w += w0 * v0.w;
        a1.x += w1 * v1.x; a1.y += w1 * v1.y; a1.z += w1 * v1.z; a1.w += w1 * v1.w;
    }
    if (j < end) {
        int2 s0 = sw[j];
        float4 v0 = x4[(size_t)s0.x * 32 + fl];
        float w0 = __int_as_float(s0.y);
        a0.x += w0 * v0.x; a0.y += w0 * v0.y; a0.z += w0 * v0.z; a0.w += w0 * v0.w;
    }
    float4 r = make_float4(a0.x + a1.x, a0.y + a1.y, a0.z + a1.z, a0.w + a1.w);
    ((float4*)out)[(size_t)node * 32 + fl] = r;
}

// ---- f16 MFMA GEMM (top): out = [aggh|xh] @ Wf^T + b -----------------------
// 256 thr = 4 waves, tile 128 rows x 128 cols, K=256 in 4 chunks of 64.
// LDS 32KB (At + Wt, f16, 16B-block XOR swizzle) -> 5 blocks/CU.
__global__ __launch_bounds__(256) void mfma_f16_kernel(
    const short* __restrict__ xh, const short* __restrict__ Wf,
    const float* __restrict__ bias, float* __restrict__ out)
{
    __shared__ short lds[2 * 128 * 64];   // At, Wt : 32 KB
    short* At = lds;
    short* Wt = lds + 8192;

    const int tid  = threadIdx.x;
    const int lane = tid & 63;
    const int wave = tid >> 6;
    const int row0 = blockIdx.x * 128;
    const int frow = lane & 15;

    floatx4 acc[2][8];
    #pragma unroll
    for (int nf = 0; nf < 8; nf++) {
        float b = bias[nf * 16 + frow];
        #pragma unroll
        for (int mf = 0; mf < 2; mf++) acc[mf][nf] = (floatx4){b, b, b, b};
    }

    const short* aggh = (const short*)out;   // f16 view; row n tail = [n*256+128, n*256+256)

    for (int kc = 0; kc < 4; kc++) {
        __syncthreads();
        #pragma unroll
        for (int i = 0; i < 4; i++) {
            int e = (i * 256 + tid) * 8;
            int r = e >> 6, k = e & 63;
            int rg = row0 + r;
            short8v v = (short8v)0;
            if (rg < NN) {
                if (kc < 2) v = *(const short8v*)&aggh[(size_t)rg * 256 + 128 + kc * 64 + k];
                else        v = *(const short8v*)&xh[(size_t)rg * 128 + (kc - 2) * 64 + k];
            }
            int sidx = r * 64 + (((k >> 3) ^ (r & 7)) << 3);
            *(short8v*)&At[sidx] = v;
        }
        #pragma unroll
        for (int i = 0; i < 4; i++) {
            int e = (i * 256 + tid) * 8;
            int c = e >> 6, k = e & 63;
            int sidx = c * 64 + (((k >> 3) ^ (c & 7)) << 3);
            *(short8v*)&Wt[sidx] = *(const short8v*)&Wf[c * 256 + kc * 64 + k];
        }
        __syncthreads();

        const int arow = wave * 32;
        #pragma unroll
        for (int kf = 0; kf < 2; kf++) {
            const int kblk = kf * 4 + (lane >> 4);
            half8v a[2];
            #pragma unroll
            for (int mf = 0; mf < 2; mf++) {
                int r = arow + mf * 16 + frow;
                int idx = r * 64 + ((kblk ^ (r & 7)) << 3);
                a[mf] = *(const half8v*)&At[idx];
            }
            #pragma unroll
            for (int nf = 0; nf < 8; nf++) {
                int cc = nf * 16 + frow;
                int idx = cc * 64 + ((kblk ^ (cc & 7)) << 3);
                half8v b = *(const half8v*)&Wt[idx];
                #pragma unroll
                for (int mf = 0; mf < 2; mf++)
                    acc[mf][nf] = __builtin_amdgcn_mfma_f32_16x16x32_f16(a[mf], b, acc[mf][nf], 0, 0, 0);
            }
        }
    }

    const int orow = row0 + wave * 32;
    #pragma unroll
    for (int mf = 0; mf < 2; mf++) {
        #pragma unroll
        for (int j = 0; j < 4; j++) {
            int r = orow + mf * 16 + (lane >> 4) * 4 + j;
            if (r < NN) {
                #pragma unroll
                for (int nf = 0; nf < 8; nf++)
                    out[(size_t)r * D + nf * 16 + (lane & 15)] = acc[mf][nf][j];
            }
        }
    }
}

// ---- mid-tier MFMA GEMM (split-bf16 3-term, R4 path) -----------------------
__global__ __launch_bounds__(256) void mfma_gemm_kernel(
    const float* __restrict__ x, const short* __restrict__ Wb,
    const float* __restrict__ bias, float* __restrict__ out)
{
    __shared__ short lds[4 * 128 * 64];
    short* Ah = lds;
    short* Al = lds + 8192;
    short* Wh = lds + 16384;
    short* Wl = lds + 24576;

    const int tid  = threadIdx.x;
    const int lane = tid & 63;
    const int wave = tid >> 6;
    const int row0 = blockIdx.x * 128;
    const int frow = lane & 15;
    const int fk   = (lane >> 4) * 8;

    floatx4 acc[2][8];
    #pragma unroll
    for (int nf = 0; nf < 8; nf++) {
        float b = bias[nf * 16 + frow];
        #pragma unroll
        for (int mf = 0; mf < 2; mf++) acc[mf][nf] = (floatx4){b, b, b, b};
    }

    for (int kc = 0; kc < 4; kc++) {
        const float* A = (kc < 2) ? out : x;
        const int kcol = (kc & 1) * 64;
        __syncthreads();
        #pragma unroll
        for (int i = 0; i < 8; i++) {
            int e = (i * 256 + tid) * 4;
            int r = e >> 6, k = e & 63;
            int rg = row0 + r;
            float4 v = (rg < NN) ? *(const float4*)&A[(size_t)rg * D + kcol + k]
                                 : make_float4(0.f, 0.f, 0.f, 0.f);
            short4 h, l;
            split_bf16(v.x, h.x, l.x);
            split_bf16(v.y, h.y, l.y);
            split_bf16(v.z, h.z, l.z);
            split_bf16(v.w, h.w, l.w);
            int sidx = r * 64 + (((k >> 3) ^ (r & 7)) << 3) + (k & 7);
            *(short4*)&Ah[sidx] = h;
            *(short4*)&Al[sidx] = l;
        }
        #pragma unroll
        for (int i = 0; i < 4; i++) {
            int e = (i * 256 + tid) * 8;
            int c = e >> 6, k = e & 63;
            int sidx = c * 64 + (((k >> 3) ^ (c & 7)) << 3);
            int g = c * 256 + kc * 64 + k;
            *(short8v*)&Wh[sidx] = *(const short8v*)&Wb[g];
            *(short8v*)&Wl[sidx] = *(const short8v*)&Wb[32768 + g];
        }
        __syncthreads();

        const int arow = wave * 32;
        #pragma unroll
        for (int kf = 0; kf < 2; kf++) {
            const int kblk = (kf * 32 + fk) >> 3;
            short8v ah[2], al[2];
            #pragma unroll
            for (int mf = 0; mf < 2; mf++) {
                int r = arow + mf * 16 + frow;
                int idx = r * 64 + ((kblk ^ (r & 7)) << 3);
                ah[mf] = *(const short8v*)&Ah[idx];
                al[mf] = *(const short8v*)&Al[idx];
            }
            #pragma unroll
            for (int nf = 0; nf < 8; nf++) {
                int cc = nf * 16 + frow;
                int idx = cc * 64 + ((kblk ^ (cc & 7)) << 3);
                short8v bh = *(const short8v*)&Wh[idx];
                short8v bl = *(const short8v*)&Wl[idx];
                #pragma unroll
                for (int mf = 0; mf < 2; mf++) {
                    acc[mf][nf] = __builtin_amdgcn_mfma_f32_16x16x32_bf16(ah[mf], bh, acc[mf][nf], 0, 0, 0);
                    acc[mf][nf] = __builtin_amdgcn_mfma_f32_16x16x32_bf16(al[mf], bh, acc[mf][nf], 0, 0, 0);
                    acc[mf][nf] = __builtin_amdgcn_mfma_f32_16x16x32_bf16(ah[mf], bl, acc[mf][nf], 0, 0, 0);
                }
            }
        }
    }

    const int orow = row0 + wave * 32;
    #pragma unroll
    for (int mf = 0; mf < 2; mf++) {
        #pragma unroll
        for (int j = 0; j < 4; j++) {
            int r = orow + mf * 16 + (lane >> 4) * 4 + j;
            if (r < NN) {
                #pragma unroll
                for (int nf = 0; nf < 8; nf++)
                    out[(size_t)r * D + nf * 16 + (lane & 15)] = acc[mf][nf][j];
            }
        }
    }
}

// ---- fallback fp32 GEMM (atomic tier only) ---------------------------------
__global__ __launch_bounds__(512) void gemm_kernel(
    const float* __restrict__ x, const float* __restrict__ Wrel,
    const float* __restrict__ Wroot, const float* __restrict__ bias,
    float* out)
{
    __shared__ float AtT[128][65];
    const int tid  = threadIdx.x;
    const int lane = tid & 63;
    const int wid  = __builtin_amdgcn_readfirstlane(tid >> 6);
    const int row0 = blockIdx.x * 64;
    float acc[16];
    {
        const float* bb = bias + wid * 16;
        #pragma unroll
        for (int c = 0; c < 16; c++) acc[c] = bb[c];
    }
    for (int phase = 0; phase < 2; phase++) {
        const float* A = phase ? x : out;
        const float* W = (phase ? Wroot : Wrel) + wid * 16 * D;
        __syncthreads();
        #pragma unroll
        for (int i = 0; i < 16; i++) {
            int e = i * 512 + tid;
            int r = e >> 7, k = e & 127;
            int rg = row0 + r;
            AtT[k][r] = (rg < NN) ? A[rg * D + k] : 0.0f;
        }
        __syncthreads();
        for (int k4 = 0; k4 < 32; k4++) {
            float a0 = AtT[k4 * 4 + 0][lane];
            float a1 = AtT[k4 * 4 + 1][lane];
            float a2 = AtT[k4 * 4 + 2][lane];
            float a3 = AtT[k4 * 4 + 3][lane];
            #pragma unroll
            for (int c = 0; c < 16; c++) {
                const float* wp = W + c * D + k4 * 4;
                acc[c] += a0 * wp[0] + a1 * wp[1] + a2 * wp[2] + a3 * wp[3];
            }
        }
    }
    __syncthreads();
    #pragma unroll
    for (int c = 0; c < 16; c++)
        AtT[wid * 16 + c][lane] = acc[c];
    __syncthreads();
    #pragma unroll
    for (int i = 0; i < 16; i++) {
        int e = i * 512 + tid;
        int r = e >> 7, col = e & 127;
        int rg = row0 + r;
        if (rg < NN) out[rg * D + col] = AtT[col][r];
    }
}

extern "C" void kernel_launch(void* const* d_in, const int* in_sizes, int n_in,
                              void* d_out, int out_size, void* d_ws, size_t ws_size,
                              hipStream_t stream) {
    const float* x     = (const float*)d_in[0];
    const int*   ei    = (const int*)  d_in[1];
    const float* ew    = (const float*)d_in[2];
    const float* Wrel  = (const float*)d_in[3];
    const float* Wroot = (const float*)d_in[4];
    const float* bias  = (const float*)d_in[5];
    float*       out   = (float*)d_out;

    const int eb = (EE + 255) / 256;

    if (ws_size >= (size_t)WS_INTS_TOP * sizeof(int)) {
        int* w = (int*)d_ws;
        int*   cnt  = w + WS_CNT;
        int*   offs = w + WS_OFFS;
        int*   bsum = w + WS_BSUM;
        int2*  sw   = (int2*)(w + WS_SW);
        short* Wf   = (short*)(w + WS_WF);
        short* xh   = (short*)(w + WS_XH);

        zero_cnt_kernel<<<(NBINS + 255) / 256, 256, 0, stream>>>(cnt);
        prep_kernel<<<PREP_XB + PREP_WB + PREP_HB, 256, 0, stream>>>(
            x, Wrel, Wroot, ei, xh, Wf, cnt);
        scanA_kernel<<<SCAN_NBLK, 256, 0, stream>>>(cnt, offs, bsum);
        scanC_kernel<<<SCAN_NBLK, 256, 0, stream>>>(offs, bsum);
        build_kernel<<<eb, 256, 0, stream>>>(ei, ew, offs, sw);
        aggregate_h_kernel<<<NN / 8, 256, 0, stream>>>(xh, offs, sw, out);
        mfma_f16_kernel<<<(NN + 127) / 128, 256, 0, stream>>>(xh, Wf, bias, out);
    } else if (ws_size >= (size_t)WS_INTS_MID * sizeof(int)) {
        int* w = (int*)d_ws;
        int*   cnt  = w + WS_CNT;
        int*   offs = w + WS_OFFS;
        int*   bsum = w + WS_BSUM;
        int2*  sw   = (int2*)(w + WS_SW);
        short* Wb   = (short*)(w + WS_WCONV);

        zero_cnt_kernel<<<(NBINS + 255) / 256, 256, 0, stream>>>(cnt);
        wconv_kernel<<<128, 256, 0, stream>>>(Wrel, Wroot, Wb);
        hist_kernel <<<eb, 256, 0, stream>>>(ei, cnt);
        scanA_kernel<<<SCAN_NBLK, 256, 0, stream>>>(cnt, offs, bsum);
        scanC_kernel<<<SCAN_NBLK, 256, 0, stream>>>(offs, bsum);
        build_kernel<<<eb, 256, 0, stream>>>(ei, ew, offs, sw);
        aggregate_kernel<<<NN / 8, 256, 0, stream>>>(x, offs, sw, out);
        mfma_gemm_kernel<<<(NN + 127) / 128, 256, 0, stream>>>(x, Wb, bias, out);
    } else {
        hipMemsetAsync(out, 0, (size_t)NN * D * sizeof(float), stream);
        scatter_kernel<<<(EE * 128) / 256, 256, 0, stream>>>(x, ei, ew, out);
        gemm_kernel<<<(NN + 63) / 64, 512, 0, stream>>>(x, Wrel, Wroot, bias, out);
    }
}

// Round 8
// 130.405 us; speedup vs baseline: 3.5372x; 1.0655x over previous
//
#include <hip/hip_runtime.h>
#include <hip/hip_fp16.h>

#define NN 100000
#define EE 640000
#define D 128
#define NBINS NN
#define SCAN_NBLK 98          // ceil(100000/1024)

#define CSTRIDE 100352        // cnt8 copy stride (ints)
#define OSTRIDE 100032        // offsx copy stride (ints)

// ---------------------------------------------------------------------------
// TOP-tier workspace layout (4-byte units):
//   cnt8  [0      , 802816)    8 XCD-local histograms (zeroed each call)
//   offsx [802816 , 1603072)   8 x (offs[bin] + prefix over copies<cp)
//                              copy 0 = plain CSR offsets; offsx[NN] = E
//   bsum  [1603072, 1603200)   per-scan-block sums
//   eslot [1603200, 2243200)   per-edge (slot<<3)|copy
//   sw    [2243200, 3523200)   packed (src, w) int2, dst-sorted
//   Wf    [3523200, 3539584)   W as f16 [128 c][256 k]
//   xh    [3539584, 9939584)   x as f16 [100000][128]
// agg (f16) lives in the upper 256B of each 512B out row.
// ---------------------------------------------------------------------------
#define WS_CNT8     0
#define WS_OFFSX    802816
#define WS_BSUM     1603072
#define WS_ESLOT    1603200
#define WS_SW       2243200
#define WS_WF       3523200
#define WS_XH       3539584
#define WS_INTS_TOP 9939584

// MID-tier (R4 fp32 path) layout
#define WS_CNT      0
#define WS_OFFS     100000
#define WS_BSUMM    200000
#define WS_SWM      200192
#define WS_WCONV    1480192
#define WS_INTS_MID 1512960

// prep_kernel block partition
#define PREP_XB 3125          // x->fp16 : 3125*256*16 = 12.8M elems
#define PREP_WB 128           // W->f16  : 128*256     = 32768 elems
#define PREP_HB 2500          // hist    : 2500*256    = 640K edges

typedef __attribute__((ext_vector_type(8))) short    short8v;
typedef __attribute__((ext_vector_type(8))) _Float16 half8v;
typedef __attribute__((ext_vector_type(4))) float    floatx4;
struct __align__(8) half4t { __half2 a, b; };

__device__ inline void split_bf16(float f, short& h, short& l) {
    unsigned u  = __float_as_uint(f);
    unsigned hb = u & 0xFFFF0000u;
    h = (short)(u >> 16);
    float fl = f - __uint_as_float(hb);
    l = (short)(__float_as_uint(fl) >> 16);
}

// ---- fallback path (atomic scatter), used only if ws tiny ------------------
__global__ __launch_bounds__(256) void scatter_kernel(
    const float* __restrict__ x, const int* __restrict__ ei,
    const float* __restrict__ ew, float* agg)
{
    int gid = blockIdx.x * 256 + threadIdx.x;
    int e = gid >> 7, f = gid & 127;
    if (e >= EE) return;
    float v = x[ei[e] * D + f] * ew[e];
    unsafeAtomicAdd(&agg[ei[EE + e] * D + f], v);
}

// ---- 0. zero the replicated histogram --------------------------------------
__global__ __launch_bounds__(256) void zero8_kernel(int* __restrict__ cnt8)
{
    int i = blockIdx.x * 256 + threadIdx.x;
    if (i < 8 * CSTRIDE) cnt8[i] = 0;
}

__global__ __launch_bounds__(256) void zero_cnt_kernel(int* __restrict__ cnt)
{
    int i = blockIdx.x * 256 + threadIdx.x;
    if (i < NBINS) cnt[i] = 0;
}

// ---- fused prep: x->fp16 | W->f16 | XCD-local histogram + slot record ------
__global__ __launch_bounds__(256) void prep_kernel(
    const float* __restrict__ x, const float* __restrict__ Wrel,
    const float* __restrict__ Wroot, const int* __restrict__ ei,
    short* __restrict__ xh, short* __restrict__ Wf,
    int* __restrict__ cnt8, int* __restrict__ eslot)
{
    const int b = blockIdx.x;
    if (b < PREP_XB) {
        const int base = b * 4096 + threadIdx.x * 4;   // f32 index
        float4 v[4];
        #pragma unroll
        for (int u = 0; u < 4; u++)
            v[u] = *(const float4*)&x[base + u * 1024];
        #pragma unroll
        for (int u = 0; u < 4; u++) {
            short4 h;
            h.x = (short)__half_as_ushort(__float2half(v[u].x));
            h.y = (short)__half_as_ushort(__float2half(v[u].y));
            h.z = (short)__half_as_ushort(__float2half(v[u].z));
            h.w = (short)__half_as_ushort(__float2half(v[u].w));
            *(short4*)&xh[base + u * 1024] = h;
        }
    } else if (b < PREP_XB + PREP_WB) {
        int i = (b - PREP_XB) * 256 + threadIdx.x;   // 0..32767
        int c = i >> 8, k = i & 255;
        float f = (k < 128) ? Wrel[c * 128 + k] : Wroot[c * 128 + (k - 128)];
        Wf[i] = (short)__half_as_ushort(__float2half(f));
    } else {
        int e = (b - PREP_XB - PREP_WB) * 256 + threadIdx.x;
        if (e < EE) {
            int dst  = ei[EE + e];
            int cp   = b & 7;                       // ~XCD-local copy
            int slot = atomicAdd(&cnt8[cp * CSTRIDE + dst], 1);
            eslot[e] = (slot << 3) | cp;
        }
    }
}

// ---- scanA8: block scan of per-bin totals + per-copy replicated offsets ----
__global__ __launch_bounds__(256) void scanA8_kernel(
    const int* __restrict__ cnt8, int* __restrict__ offsx, int* __restrict__ bsum)
{
    __shared__ int tsum[256];
    const int tid = threadIdx.x;
    const int base = blockIdx.x * 1024 + tid * 4;
    int v[4], pc[8][4];
    int s = 0;
    #pragma unroll
    for (int i = 0; i < 4; i++) {
        int bin = base + i;
        int run = 0;
        #pragma unroll
        for (int cp = 0; cp < 8; cp++) {
            int cv = (bin < NBINS) ? cnt8[cp * CSTRIDE + bin] : 0;
            pc[cp][i] = run;
            run += cv;
        }
        v[i] = run;
        s += run;
    }
    tsum[tid] = s;
    __syncthreads();
    for (int off = 1; off < 256; off <<= 1) {
        int t = (tid >= off) ? tsum[tid - off] : 0;
        __syncthreads();
        tsum[tid] += t;
        __syncthreads();
    }
    int run = tsum[tid] - s;      // exclusive prefix of this thread's first bin
    #pragma unroll
    for (int i = 0; i < 4; i++) {
        int bin = base + i;
        if (bin < NBINS) {
            #pragma unroll
            for (int cp = 0; cp < 8; cp++)
                offsx[cp * OSTRIDE + bin] = run + pc[cp][i];
        }
        run += v[i];
    }
    if (tid == 255) bsum[blockIdx.x] = tsum[255];
}

// ---- scanC8: add global block prefix to all 8 copies + sentinel ------------
__global__ __launch_bounds__(256) void scanC8_kernel(
    int* __restrict__ offsx, const int* __restrict__ bsum)
{
    __shared__ int s[128];
    const int tid = threadIdx.x;
    if (tid < 128) s[tid] = (tid < SCAN_NBLK) ? bsum[tid] : 0;
    __syncthreads();
    for (int off = 1; off < 128; off <<= 1) {
        int t = 0;
        if (tid < 128 && tid >= off) t = s[tid - off];
        __syncthreads();
        if (tid < 128) s[tid] += t;
        __syncthreads();
    }
    const int add = (blockIdx.x == 0) ? 0 : s[blockIdx.x - 1];
    const int base = blockIdx.x * 1024 + tid * 4;
    #pragma unroll
    for (int i = 0; i < 4; i++) {
        int bin = base + i;
        if (bin < NBINS) {
            #pragma unroll
            for (int cp = 0; cp < 8; cp++)
                offsx[cp * OSTRIDE + bin] += add;
        }
    }
    if (blockIdx.x == 0 && tid == 0) offsx[NN] = EE;   // copy-0 sentinel
}

// ---- build (atomic-free): p = offsx[copy][dst] + slot ----------------------
__global__ __launch_bounds__(256) void build_kernel(
    const int* __restrict__ ei, const float* __restrict__ ew,
    const int* __restrict__ offsx, const int* __restrict__ eslot,
    int2* __restrict__ sw)
{
    int e = blockIdx.x * 256 + threadIdx.x;
    if (e >= EE) return;
    int dst = ei[EE + e];
    int es  = eslot[e];
    int p   = offsx[(es & 7) * OSTRIDE + dst] + (es >> 3);
    sw[p] = make_int2(ei[e], __float_as_int(ew[e]));
}

// ---- aggregate (top): fp16 gather 4-deep, f16 agg into out-row tail --------
__global__ __launch_bounds__(256) void aggregate_h_kernel(
    const short* __restrict__ xh, const int* __restrict__ offsx,
    const int2* __restrict__ sw, float* __restrict__ out)
{
    const int node = blockIdx.x * 8 + (threadIdx.x >> 5);
    const int fl   = threadIdx.x & 31;
    if (node >= NN) return;
    const int beg = offsx[node];       // copy-0 = plain exclusive offsets
    const int end = offsx[node + 1];
    const half4t* xp = (const half4t*)xh;

    float4 a0 = make_float4(0.f, 0.f, 0.f, 0.f);
    float4 a1 = make_float4(0.f, 0.f, 0.f, 0.f);
    int j = beg;
    for (; j + 3 < end; j += 4) {
        int2 s0 = sw[j], s1 = sw[j + 1], s2 = sw[j + 2], s3 = sw[j + 3];
        half4t v0 = xp[(size_t)s0.x * 32 + fl];
        half4t v1 = xp[(size_t)s1.x * 32 + fl];
        half4t v2 = xp[(size_t)s2.x * 32 + fl];
        half4t v3 = xp[(size_t)s3.x * 32 + fl];
        float w0 = __int_as_float(s0.y), w1 = __int_as_float(s1.y);
        float w2 = __int_as_float(s2.y), w3 = __int_as_float(s3.y);
        float2 l0 = __half22float2(v0.a), h0 = __half22float2(v0.b);
        float2 l1 = __half22float2(v1.a), h1 = __half22float2(v1.b);
        float2 l2 = __half22float2(v2.a), h2 = __half22float2(v2.b);
        float2 l3 = __half22float2(v3.a), h3 = __half22float2(v3.b);
        a0.x += w0 * l0.x; a0.y += w0 * l0.y; a0.z += w0 * h0.x; a0.w += w0 * h0.y;
        a1.x += w1 * l1.x; a1.y += w1 * l1.y; a1.z += w1 * h1.x; a1.w += w1 * h1.y;
        a0.x += w2 * l2.x; a0.y += w2 * l2.y; a0.z += w2 * h2.x; a0.w += w2 * h2.y;
        a1.x += w3 * l3.x; a1.y += w3 * l3.y; a1.z += w3 * h3.x; a1.w += w3 * h3.y;
    }
    for (; j + 1 < end; j += 2) {
        int2 s0 = sw[j], s1 = sw[j + 1];
        half4t v0 = xp[(size_t)s0.x * 32 + fl];
        half4t v1 = xp[(size_t)s1.x * 32 + fl];
        float w0 = __int_as_float(s0.y), w1 = __int_as_float(s1.y);
        float2 l0 = __half22float2(v0.a), h0 = __half22float2(v0.b);
        float2 l1 = __half22float2(v1.a), h1 = __half22float2(v1.b);
        a0.x += w0 * l0.x; a0.y += w0 * l0.y; a0.z += w0 * h0.x; a0.w += w0 * h0.y;
        a1.x += w1 * l1.x; a1.y += w1 * l1.y; a1.z += w1 * h1.x; a1.w += w1 * h1.y;
    }
    if (j < end) {
        int2 s0 = sw[j];
        half4t v0 = xp[(size_t)s0.x * 32 + fl];
        float w0 = __int_as_float(s0.y);
        float2 l0 = __half22float2(v0.a), h0 = __half22float2(v0.b);
        a0.x += w0 * l0.x; a0.y += w0 * l0.y; a0.z += w0 * h0.x; a0.w += w0 * h0.y;
    }
    float4 r = make_float4(a0.x + a1.x, a0.y + a1.y, a0.z + a1.z, a0.w + a1.w);
    half4t o;
    o.a = __floats2half2_rn(r.x, r.y);
    o.b = __floats2half2_rn(r.z, r.w);
    half4t* op = (half4t*)((char*)out + (size_t)node * 512 + 256);
    op[fl] = o;
}

// ---- f16 MFMA GEMM (top): out = [aggh|xh] @ Wf^T + b -----------------------
__global__ __launch_bounds__(256) void mfma_f16_kernel(
    const short* __restrict__ xh, const short* __restrict__ Wf,
    const float* __restrict__ bias, float* __restrict__ out)
{
    __shared__ short lds[2 * 128 * 64];   // At, Wt : 32 KB
    short* At = lds;
    short* Wt = lds + 8192;

    const int tid  = threadIdx.x;
    const int lane = tid & 63;
    const int wave = tid >> 6;
    const int row0 = blockIdx.x * 128;
    const int frow = lane & 15;

    floatx4 acc[2][8];
    #pragma unroll
    for (int nf = 0; nf < 8; nf++) {
        float b = bias[nf * 16 + frow];
        #pragma unroll
        for (int mf = 0; mf < 2; mf++) acc[mf][nf] = (floatx4){b, b, b, b};
    }

    const short* aggh = (const short*)out;   // row n tail = [n*256+128, n*256+256)

    for (int kc = 0; kc < 4; kc++) {
        __syncthreads();
        #pragma unroll
        for (int i = 0; i < 4; i++) {
            int e = (i * 256 + tid) * 8;
            int r = e >> 6, k = e & 63;
            int rg = row0 + r;
            short8v v = (short8v)0;
            if (rg < NN) {
                if (kc < 2) v = *(const short8v*)&aggh[(size_t)rg * 256 + 128 + kc * 64 + k];
                else        v = *(const short8v*)&xh[(size_t)rg * 128 + (kc - 2) * 64 + k];
            }
            int sidx = r * 64 + (((k >> 3) ^ (r & 7)) << 3);
            *(short8v*)&At[sidx] = v;
        }
        #pragma unroll
        for (int i = 0; i < 4; i++) {
            int e = (i * 256 + tid) * 8;
            int c = e >> 6, k = e & 63;
            int sidx = c * 64 + (((k >> 3) ^ (c & 7)) << 3);
            *(short8v*)&Wt[sidx] = *(const short8v*)&Wf[c * 256 + kc * 64 + k];
        }
        __syncthreads();

        const int arow = wave * 32;
        #pragma unroll
        for (int kf = 0; kf < 2; kf++) {
            const int kblk = kf * 4 + (lane >> 4);
            half8v a[2];
            #pragma unroll
            for (int mf = 0; mf < 2; mf++) {
                int r = arow + mf * 16 + frow;
                int idx = r * 64 + ((kblk ^ (r & 7)) << 3);
                a[mf] = *(const half8v*)&At[idx];
            }
            #pragma unroll
            for (int nf = 0; nf < 8; nf++) {
                int cc = nf * 16 + frow;
                int idx = cc * 64 + ((kblk ^ (cc & 7)) << 3);
                half8v b = *(const half8v*)&Wt[idx];
                #pragma unroll
                for (int mf = 0; mf < 2; mf++)
                    acc[mf][nf] = __builtin_amdgcn_mfma_f32_16x16x32_f16(a[mf], b, acc[mf][nf], 0, 0, 0);
            }
        }
    }

    const int orow = row0 + wave * 32;
    #pragma unroll
    for (int mf = 0; mf < 2; mf++) {
        #pragma unroll
        for (int j = 0; j < 4; j++) {
            int r = orow + mf * 16 + (lane >> 4) * 4 + j;
            if (r < NN) {
                #pragma unroll
                for (int nf = 0; nf < 8; nf++)
                    out[(size_t)r * D + nf * 16 + (lane & 15)] = acc[mf][nf][j];
            }
        }
    }
}

// ======================= MID-tier kernels (R4 fp32 path) =====================
__global__ __launch_bounds__(256) void hist_kernel(
    const int* __restrict__ ei, int* __restrict__ cnt)
{
    int e = blockIdx.x * 256 + threadIdx.x;
    if (e < EE) atomicAdd(&cnt[ei[EE + e]], 1);
}

__global__ __launch_bounds__(256) void wconv_kernel(
    const float* __restrict__ Wrel, const float* __restrict__ Wroot,
    short* __restrict__ Wb)
{
    int i = blockIdx.x * 256 + threadIdx.x;
    int c = i >> 8, k = i & 255;
    float f = (k < 128) ? Wrel[c * 128 + k] : Wroot[c * 128 + (k - 128)];
    short h, l;
    split_bf16(f, h, l);
    Wb[i] = h;
    Wb[32768 + i] = l;
}

__global__ __launch_bounds__(256) void scanA_kernel(
    const int* __restrict__ cnt, int* __restrict__ offs, int* __restrict__ bsum)
{
    __shared__ int tsum[256];
    const int tid = threadIdx.x;
    const int base = blockIdx.x * 1024 + tid * 4;
    int v[4], s = 0;
    #pragma unroll
    for (int i = 0; i < 4; i++) {
        int idx = base + i;
        v[i] = (idx < NBINS) ? cnt[idx] : 0;
        s += v[i];
    }
    tsum[tid] = s;
    __syncthreads();
    for (int off = 1; off < 256; off <<= 1) {
        int t = (tid >= off) ? tsum[tid - off] : 0;
        __syncthreads();
        tsum[tid] += t;
        __syncthreads();
    }
    int run = tsum[tid] - s;
    #pragma unroll
    for (int i = 0; i < 4; i++) {
        int idx = base + i;
        if (idx < NBINS) offs[idx] = run;
        run += v[i];
    }
    if (tid == 255) bsum[blockIdx.x] = tsum[255];
}

__global__ __launch_bounds__(256) void scanC_kernel(
    int* __restrict__ offs, const int* __restrict__ bsum)
{
    __shared__ int s[128];
    const int tid = threadIdx.x;
    if (tid < 128) s[tid] = (tid < SCAN_NBLK) ? bsum[tid] : 0;
    __syncthreads();
    for (int off = 1; off < 128; off <<= 1) {
        int t = 0;
        if (tid < 128 && tid >= off) t = s[tid - off];
        __syncthreads();
        if (tid < 128) s[tid] += t;
        __syncthreads();
    }
    const int add = (blockIdx.x == 0) ? 0 : s[blockIdx.x - 1];
    const int base = blockIdx.x * 1024 + tid * 4;
    #pragma unroll
    for (int i = 0; i < 4; i++) {
        int idx = base + i;
        if (idx < NBINS) offs[idx] += add;
    }
}

__global__ __launch_bounds__(256) void buildM_kernel(
    const int* __restrict__ ei, const float* __restrict__ ew,
    int* __restrict__ offs, int2* __restrict__ sw)
{
    int e = blockIdx.x * 256 + threadIdx.x;
    if (e >= EE) return;
    int dst = ei[EE + e];
    int p = atomicAdd(&offs[dst], 1);
    sw[p] = make_int2(ei[e], __float_as_int(ew[e]));
}

__global__ __launch_bounds__(256) void aggregate_kernel(
    const float* __restrict__ x, const int* __restrict__ offs,
    const int2* __restrict__ sw, float* __restrict__ out)
{
    const int node = blockIdx.x * 8 + (threadIdx.x >> 5);
    const int fl   = threadIdx.x & 31;
    if (node >= NN) return;
    const int beg = (node == 0) ? 0 : offs[node - 1];
    const int end = offs[node];
    const float4* x4 = (const float4*)x;

    float4 a0 = make_float4(0.f, 0.f, 0.f, 0.f);
    float4 a1 = make_float4(0.f, 0.f, 0.f, 0.f);
    int j = beg;
    for (; j + 1 < end; j += 2) {
        int2 s0 = sw[j];
        int2 s1 = sw[j + 1];
        float4 v0 = x4[(size_t)s0.x * 32 + fl];
        float4 v1 = x4[(size_t)s1.x * 32 + fl];
        float w0 = __int_as_float(s0.y), w1 = __int_as_float(s1.y);
        a0.x += w0 * v0.x; a0.y += w0 * v0.y; a0.z += w0 * v0.z; a0.w += w0 * v0.w;
        a1.x += w1 * v1.x; a1.y += w1 * v1.y; a1.z += w1 * v1.z; a1.w += w1 * v1.w;
    }
    if (j < end) {
        int2 s0 = sw[j];
        float4 v0 = x4[(size_t)s0.x * 32 + fl];
        float w0 = __int_as_float(s0.y);
        a0.x += w0 * v0.x; a0.y += w0 * v0.y; a0.z += w0 * v0.z; a0.w += w0 * v0.w;
    }
    float4 r = make_float4(a0.x + a1.x, a0.y + a1.y, a0.z + a1.z, a0.w + a1.w);
    ((float4*)out)[(size_t)node * 32 + fl] = r;
}

__global__ __launch_bounds__(256) void mfma_gemm_kernel(
    const float* __restrict__ x, const short* __restrict__ Wb,
    const float* __restrict__ bias, float* __restrict__ out)
{
    __shared__ short lds[4 * 128 * 64];
    short* Ah = lds;
    short* Al = lds + 8192;
    short* Wh = lds + 16384;
    short* Wl = lds + 24576;

    const int tid  = threadIdx.x;
    const int lane = tid & 63;
    const int wave = tid >> 6;
    const int row0 = blockIdx.x * 128;
    const int frow = lane & 15;
    const int fk   = (lane >> 4) * 8;

    floatx4 acc[2][8];
    #pragma unroll
    for (int nf = 0; nf < 8; nf++) {
        float b = bias[nf * 16 + frow];
        #pragma unroll
        for (int mf = 0; mf < 2; mf++) acc[mf][nf] = (floatx4){b, b, b, b};
    }

    for (int kc = 0; kc < 4; kc++) {
        const float* A = (kc < 2) ? out : x;
        const int kcol = (kc & 1) * 64;
        __syncthreads();
        #pragma unroll
        for (int i = 0; i < 8; i++) {
            int e = (i * 256 + tid) * 4;
            int r = e >> 6, k = e & 63;
            int rg = row0 + r;
            float4 v = (rg < NN) ? *(const float4*)&A[(size_t)rg * D + kcol + k]
                                 : make_float4(0.f, 0.f, 0.f, 0.f);
            short4 h, l;
            split_bf16(v.x, h.x, l.x);
            split_bf16(v.y, h.y, l.y);
            split_bf16(v.z, h.z, l.z);
            split_bf16(v.w, h.w, l.w);
            int sidx = r * 64 + (((k >> 3) ^ (r & 7)) << 3) + (k & 7);
            *(short4*)&Ah[sidx] = h;
            *(short4*)&Al[sidx] = l;
        }
        #pragma unroll
        for (int i = 0; i < 4; i++) {
            int e = (i * 256 + tid) * 8;
            int c = e >> 6, k = e & 63;
            int sidx = c * 64 + (((k >> 3) ^ (c & 7)) << 3);
            int g = c * 256 + kc * 64 + k;
            *(short8v*)&Wh[sidx] = *(const short8v*)&Wb[g];
            *(short8v*)&Wl[sidx] = *(const short8v*)&Wb[32768 + g];
        }
        __syncthreads();

        const int arow = wave * 32;
        #pragma unroll
        for (int kf = 0; kf < 2; kf++) {
            const int kblk = (kf * 32 + fk) >> 3;
            short8v ah[2], al[2];
            #pragma unroll
            for (int mf = 0; mf < 2; mf++) {
                int r = arow + mf * 16 + frow;
                int idx = r * 64 + ((kblk ^ (r & 7)) << 3);
                ah[mf] = *(const short8v*)&Ah[idx];
                al[mf] = *(const short8v*)&Al[idx];
            }
            #pragma unroll
            for (int nf = 0; nf < 8; nf++) {
                int cc = nf * 16 + frow;
                int idx = cc * 64 + ((kblk ^ (cc & 7)) << 3);
                short8v bh = *(const short8v*)&Wh[idx];
                short8v bl = *(const short8v*)&Wl[idx];
                #pragma unroll
                for (int mf = 0; mf < 2; mf++) {
                    acc[mf][nf] = __builtin_amdgcn_mfma_f32_16x16x32_bf16(ah[mf], bh, acc[mf][nf], 0, 0, 0);
                    acc[mf][nf] = __builtin_amdgcn_mfma_f32_16x16x32_bf16(al[mf], bh, acc[mf][nf], 0, 0, 0);
                    acc[mf][nf] = __builtin_amdgcn_mfma_f32_16x16x32_bf16(ah[mf], bl, acc[mf][nf], 0, 0, 0);
                }
            }
        }
    }

    const int orow = row0 + wave * 32;
    #pragma unroll
    for (int mf = 0; mf < 2; mf++) {
        #pragma unroll
        for (int j = 0; j < 4; j++) {
            int r = orow + mf * 16 + (lane >> 4) * 4 + j;
            if (r < NN) {
                #pragma unroll
                for (int nf = 0; nf < 8; nf++)
                    out[(size_t)r * D + nf * 16 + (lane & 15)] = acc[mf][nf][j];
            }
        }
    }
}

// ---- fallback fp32 GEMM (atomic tier only) ---------------------------------
__global__ __launch_bounds__(512) void gemm_kernel(
    const float* __restrict__ x, const float* __restrict__ Wrel,
    const float* __restrict__ Wroot, const float* __restrict__ bias,
    float* out)
{
    __shared__ float AtT[128][65];
    const int tid  = threadIdx.x;
    const int lane = tid & 63;
    const int wid  = __builtin_amdgcn_readfirstlane(tid >> 6);
    const int row0 = blockIdx.x * 64;
    float acc[16];
    {
        const float* bb = bias + wid * 16;
        #pragma unroll
        for (int c = 0; c < 16; c++) acc[c] = bb[c];
    }
    for (int phase = 0; phase < 2; phase++) {
        const float* A = phase ? x : out;
        const float* W = (phase ? Wroot : Wrel) + wid * 16 * D;
        __syncthreads();
        #pragma unroll
        for (int i = 0; i < 16; i++) {
            int e = i * 512 + tid;
            int r = e >> 7, k = e & 127;
            int rg = row0 + r;
            AtT[k][r] = (rg < NN) ? A[rg * D + k] : 0.0f;
        }
        __syncthreads();
        for (int k4 = 0; k4 < 32; k4++) {
            float a0 = AtT[k4 * 4 + 0][lane];
            float a1 = AtT[k4 * 4 + 1][lane];
            float a2 = AtT[k4 * 4 + 2][lane];
            float a3 = AtT[k4 * 4 + 3][lane];
            #pragma unroll
            for (int c = 0; c < 16; c++) {
                const float* wp = W + c * D + k4 * 4;
                acc[c] += a0 * wp[0] + a1 * wp[1] + a2 * wp[2] + a3 * wp[3];
            }
        }
    }
    __syncthreads();
    #pragma unroll
    for (int c = 0; c < 16; c++)
        AtT[wid * 16 + c][lane] = acc[c];
    __syncthreads();
    #pragma unroll
    for (int i = 0; i < 16; i++) {
        int e = i * 512 + tid;
        int r = e >> 7, col = e & 127;
        int rg = row0 + r;
        if (rg < NN) out[rg * D + col] = AtT[col][r];
    }
}

extern "C" void kernel_launch(void* const* d_in, const int* in_sizes, int n_in,
                              void* d_out, int out_size, void* d_ws, size_t ws_size,
                              hipStream_t stream) {
    const float* x     = (const float*)d_in[0];
    const int*   ei    = (const int*)  d_in[1];
    const float* ew    = (const float*)d_in[2];
    const float* Wrel  = (const float*)d_in[3];
    const float* Wroot = (const float*)d_in[4];
    const float* bias  = (const float*)d_in[5];
    float*       out   = (float*)d_out;

    const int eb = (EE + 255) / 256;

    if (ws_size >= (size_t)WS_INTS_TOP * sizeof(int)) {
        int* w = (int*)d_ws;
        int*   cnt8  = w + WS_CNT8;
        int*   offsx = w + WS_OFFSX;
        int*   bsum  = w + WS_BSUM;
        int*   eslot = w + WS_ESLOT;
        int2*  sw    = (int2*)(w + WS_SW);
        short* Wf    = (short*)(w + WS_WF);
        short* xh    = (short*)(w + WS_XH);

        zero8_kernel<<<(8 * CSTRIDE) / 256, 256, 0, stream>>>(cnt8);
        prep_kernel<<<PREP_XB + PREP_WB + PREP_HB, 256, 0, stream>>>(
            x, Wrel, Wroot, ei, xh, Wf, cnt8, eslot);
        scanA8_kernel<<<SCAN_NBLK, 256, 0, stream>>>(cnt8, offsx, bsum);
        scanC8_kernel<<<SCAN_NBLK, 256, 0, stream>>>(offsx, bsum);
        build_kernel<<<eb, 256, 0, stream>>>(ei, ew, offsx, eslot, sw);
        aggregate_h_kernel<<<NN / 8, 256, 0, stream>>>(xh, offsx, sw, out);
        mfma_f16_kernel<<<(NN + 127) / 128, 256, 0, stream>>>(xh, Wf, bias, out);
    } else if (ws_size >= (size_t)WS_INTS_MID * sizeof(int)) {
        int* w = (int*)d_ws;
        int*   cnt  = w + WS_CNT;
        int*   offs = w + WS_OFFS;
        int*   bsum = w + WS_BSUMM;
        int2*  sw   = (int2*)(w + WS_SWM);
        short* Wb   = (short*)(w + WS_WCONV);

        zero_cnt_kernel<<<(NBINS + 255) / 256, 256, 0, stream>>>(cnt);
        wconv_kernel<<<128, 256, 0, stream>>>(Wrel, Wroot, Wb);
        hist_kernel <<<eb, 256, 0, stream>>>(ei, cnt);
        scanA_kernel<<<SCAN_NBLK, 256, 0, stream>>>(cnt, offs, bsum);
        scanC_kernel<<<SCAN_NBLK, 256, 0, stream>>>(offs, bsum);
        buildM_kernel<<<eb, 256, 0, stream>>>(ei, ew, offs, sw);
        aggregate_kernel<<<NN / 8, 256, 0, stream>>>(x, offs, sw, out);
        mfma_gemm_kernel<<<(NN + 127) / 128, 256, 0, stream>>>(x, Wb, bias, out);
    } else {
        hipMemsetAsync(out, 0, (size_t)NN * D * sizeof(float), stream);
        scatter_kernel<<<(EE * 128) / 256, 256, 0, stream>>>(x, ei, ew, out);
        gemm_kernel<<<(NN + 63) / 64, 512, 0, stream>>>(x, Wrel, Wroot, bias, out);
    }
}